// Round 8
// baseline (1723.819 us; speedup 1.0000x reference)
//
#include <hip/hip_runtime.h>

#define H 32
#define DOUT 16
#define T 8     // threads per node in edge kernel
#define BLK 256

__device__ __forceinline__ float silu(float v) {
    return v * __builtin_amdgcn_rcpf(1.0f + __expf(-v));
}

// ---- CSR build: deg histogram -> exclusive scan -> scatter reordered col ---
__global__ __launch_bounds__(256) void zero_deg(int* __restrict__ deg, int N) {
    int i = blockIdx.x * blockDim.x + threadIdx.x;
    if (i < N) deg[i] = 0;
}

__global__ __launch_bounds__(256) void hist_kernel(const int* __restrict__ row,
                                                   int* __restrict__ deg, int E) {
    int e = blockIdx.x * blockDim.x + threadIdx.x;
    if (e < E) atomicAdd(&deg[row[e]], 1);
}

// single block of 1024: chunked serial sums + Hillis-Steele scan over partials
__global__ __launch_bounds__(1024) void scan_kernel(const int* __restrict__ deg,
                                                    int* __restrict__ start,
                                                    int* __restrict__ cursor, int N) {
    __shared__ int part[1024];
    int t = threadIdx.x;
    int ch = (N + 1023) >> 10;
    int lo = t * ch, hi = min(lo + ch, N);
    int s = 0;
    for (int i = lo; i < hi; ++i) s += deg[i];
    part[t] = s;
    __syncthreads();
    for (int off = 1; off < 1024; off <<= 1) {
        int v = (t >= off) ? part[t - off] : 0;
        __syncthreads();
        part[t] += v;
        __syncthreads();
    }
    int run = part[t] - s;  // exclusive prefix
    for (int i = lo; i < hi; ++i) {
        start[i] = run; cursor[i] = run;
        run += deg[i];
    }
}

// stores reordered col directly: ecol[slot] = col[e]
__global__ __launch_bounds__(256) void scatter_kernel(const int* __restrict__ row,
                                                      const int* __restrict__ col,
                                                      int* __restrict__ cursor,
                                                      int* __restrict__ ecol, int E) {
    int e = blockIdx.x * blockDim.x + threadIdx.x;
    if (e < E) {
        int p = atomicAdd(&cursor[row[e]], 1);
        ecol[p] = col[e];
    }
}

// ---- transpose edge_W2 (both layers): W2T[l][j][i] = W2[l][i][j] -----------
__global__ __launch_bounds__(256) void transpose_w2(const float* __restrict__ W2,
                                                    float* __restrict__ W2T) {
    int i = blockIdx.x * blockDim.x + threadIdx.x;
    if (i >= 2 * H * H) return;
    int l = i >> 10, r = (i >> 5) & 31, c = i & 31;   // W2[l][r][c]
    W2T[l * H * H + c * H + r] = W2[i];
}

// ---- init: x = pos@projW.T, h = attrs@embW.T + b ---------------------------
__global__ __launch_bounds__(256) void init_nodes(
    const float* __restrict__ node_attrs, const float* __restrict__ positions,
    const float* __restrict__ projW, const float* __restrict__ embW,
    const float* __restrict__ embB,
    float* __restrict__ x, float* __restrict__ h, int N)
{
    int n = blockIdx.x * blockDim.x + threadIdx.x;
    if (n >= N) return;
    float p0 = positions[3*n+0], p1 = positions[3*n+1], p2 = positions[3*n+2];
    #pragma unroll
    for (int i = 0; i < DOUT; ++i)
        x[(size_t)n*DOUT+i] = projW[i*3+0]*p0 + projW[i*3+1]*p1 + projW[i*3+2]*p2;
    float a0 = node_attrs[3*n+0], a1 = node_attrs[3*n+1], a2 = node_attrs[3*n+2];
    #pragma unroll
    for (int j = 0; j < H; ++j)
        h[(size_t)n*H+j] = embB[j] + embW[j*3+0]*a0 + embW[j*3+1]*a1 + embW[j*3+2]*a2;
}

// ---- edge kernel: T threads/node, no-spill register budget -----------------
// __launch_bounds__(BLK,2): min 2 waves/EU (8 waves/CU) -> VGPR cap ~256,
// enough for the ~170-float live set (R7 spilled at VGPR=112).
__global__ __launch_bounds__(BLK, 2) void edge_kernel(
    const int* __restrict__ start, const int* __restrict__ deg,
    const int* __restrict__ ecol,
    const float* __restrict__ positions,
    const float* __restrict__ x_in, const float* __restrict__ h_in,
    const float* __restrict__ eW1, const float* __restrict__ eb1,
    const float* __restrict__ W2T, const float* __restrict__ eb2,
    const float* __restrict__ cW1, const float* __restrict__ cb1,
    const float* __restrict__ cW2,
    float* __restrict__ xsum, float* __restrict__ magg, int N)
{
    int gid = blockIdx.x * BLK + threadIdx.x;
    int n = gid >> 3, sub = gid & (T - 1);
    if (n >= N) return;

    int s0 = start[n], dg = deg[n];

    float xr[DOUT];
    {
        const float4* xp = (const float4*)(x_in + (size_t)n * DOUT);
        #pragma unroll
        for (int q = 0; q < DOUT/4; ++q) {
            float4 v = xp[q];
            xr[4*q+0]=v.x; xr[4*q+1]=v.y; xr[4*q+2]=v.z; xr[4*q+3]=v.w;
        }
    }
    float hr[H];
    {
        const float4* hp = (const float4*)(h_in + (size_t)n * H);
        #pragma unroll
        for (int q = 0; q < H/4; ++q) {
            float4 v = hp[q];
            hr[4*q+0]=v.x; hr[4*q+1]=v.y; hr[4*q+2]=v.z; hr[4*q+3]=v.w;
        }
    }
    float pr0 = positions[3*n+0], pr1 = positions[3*n+1], pr2 = positions[3*n+2];

    float xs[DOUT];
    #pragma unroll
    for (int i = 0; i < DOUT; ++i) xs[i] = 0.0f;
    float ma[H];
    #pragma unroll
    for (int k = 0; k < H; ++k) ma[k] = 0.0f;

    for (int i = sub; i < dg; i += T) {
        int c = ecol[s0 + i];
        const float4* xc = (const float4*)(x_in + (size_t)c * DOUT);

        // radial from x[c] loads; cd NOT kept live (recomputed after cm)
        float radial = 0.0f;
        #pragma unroll
        for (int q = 0; q < DOUT/4; ++q) {
            float4 v = xc[q];
            float d0 = xr[4*q+0]-v.x, d1 = xr[4*q+1]-v.y;
            float d2 = xr[4*q+2]-v.z, d3 = xr[4*q+3]-v.w;
            radial += d0*d0; radial += d1*d1; radial += d2*d2; radial += d3*d3;
        }

        float hc[H];
        {
            const float4* hp = (const float4*)(h_in + (size_t)c * H);
            #pragma unroll
            for (int q = 0; q < H/4; ++q) {
                float4 v = hp[q];
                hc[4*q+0]=v.x; hc[4*q+1]=v.y; hc[4*q+2]=v.z; hc[4*q+3]=v.w;
            }
        }
        float ea0 = pr0 - positions[3*c+0];
        float ea1 = pr1 - positions[3*c+1];
        float ea2 = pr2 - positions[3*c+2];

        // MLP2 accumulators start at bias; MLP1 neuron j does rank-1 update
        float acc[H];
        #pragma unroll
        for (int k = 0; k < H; ++k) acc[k] = eb2[k];

        #pragma unroll 4
        for (int j = 0; j < H; ++j) {
            const float* wj = eW1 + j * 68;
            float a = eb1[j];
            #pragma unroll
            for (int k = 0; k < H; ++k) a += hr[k] * wj[k];
            #pragma unroll
            for (int k = 0; k < H; ++k) a += hc[k] * wj[32+k];
            a += radial * wj[64] + ea0 * wj[65] + ea1 * wj[66] + ea2 * wj[67];
            float m1j = silu(a);
            const float* w2j = W2T + j * H;   // column j of W2
            #pragma unroll
            for (int k = 0; k < H; ++k) acc[k] += m1j * w2j[k];
        }

        // m2 = silu(acc); aggregate
        #pragma unroll
        for (int k = 0; k < H; ++k) {
            float v = silu(acc[k]);
            acc[k] = v;
            ma[k] += v;
        }

        // coord MLP: 32 -> 32 silu -> 1
        float cm = 0.0f;
        #pragma unroll 4
        for (int j = 0; j < H; ++j) {
            const float* wj = cW1 + j * H;
            float a = cb1[j];
            #pragma unroll
            for (int k = 0; k < H; ++k) a += acc[k] * wj[k];
            cm += silu(a) * cW2[j];
        }

        // reload x[c] (L1-hot) and accumulate trans = cd * cm
        #pragma unroll
        for (int q = 0; q < DOUT/4; ++q) {
            float4 v = xc[q];
            xs[4*q+0] += (xr[4*q+0]-v.x) * cm; xs[4*q+1] += (xr[4*q+1]-v.y) * cm;
            xs[4*q+2] += (xr[4*q+2]-v.z) * cm; xs[4*q+3] += (xr[4*q+3]-v.w) * cm;
        }
    }

    // reduce partials across the T adjacent lanes of this node (same wave)
    #pragma unroll
    for (int m = 1; m < T; m <<= 1) {
        #pragma unroll
        for (int k = 0; k < H; ++k) ma[k] += __shfl_xor(ma[k], m, 64);
        #pragma unroll
        for (int i = 0; i < DOUT; ++i) xs[i] += __shfl_xor(xs[i], m, 64);
    }

    if (sub == 0) {
        float4* mo = (float4*)(magg + (size_t)n * H);
        #pragma unroll
        for (int q = 0; q < H/4; ++q) {
            float4 v; v.x=ma[4*q+0]; v.y=ma[4*q+1]; v.z=ma[4*q+2]; v.w=ma[4*q+3];
            mo[q] = v;
        }
        float4* xo = (float4*)(xsum + (size_t)n * DOUT);
        #pragma unroll
        for (int q = 0; q < DOUT/4; ++q) {
            float4 v; v.x=xs[4*q+0]; v.y=xs[4*q+1]; v.z=xs[4*q+2]; v.w=xs[4*q+3];
            xo[q] = v;
        }
    }
}

// ---- node update: x += xsum/max(deg,1); h += MLP([h, m_agg]) ---------------
__global__ __launch_bounds__(256) void node_kernel(
    const int* __restrict__ deg,
    const float* __restrict__ x_in, const float* __restrict__ h_in,
    const float* __restrict__ xsum, const float* __restrict__ magg,
    const float* __restrict__ W1, const float* __restrict__ b1,
    const float* __restrict__ W2T, const float* __restrict__ b2,
    float* __restrict__ x_out, float* __restrict__ h_out, int N)
{
    int n = blockIdx.x * blockDim.x + threadIdx.x;
    if (n >= N) return;

    float inv = __builtin_amdgcn_rcpf(fmaxf((float)deg[n], 1.0f));
    {
        const float4* xi = (const float4*)(x_in + (size_t)n * DOUT);
        const float4* xa = (const float4*)(xsum + (size_t)n * DOUT);
        float4* xo = (float4*)(x_out + (size_t)n * DOUT);
        #pragma unroll
        for (int q = 0; q < DOUT/4; ++q) {
            float4 a = xi[q], b = xa[q];
            float4 v; v.x=a.x+b.x*inv; v.y=a.y+b.y*inv; v.z=a.z+b.z*inv; v.w=a.w+b.w*inv;
            xo[q] = v;
        }
    }

    float hr[H], ma[H];
    {
        const float4* hp = (const float4*)(h_in + (size_t)n * H);
        const float4* mp = (const float4*)(magg + (size_t)n * H);
        #pragma unroll
        for (int q = 0; q < H/4; ++q) {
            float4 v = hp[q];
            hr[4*q+0]=v.x; hr[4*q+1]=v.y; hr[4*q+2]=v.z; hr[4*q+3]=v.w;
            float4 u = mp[q];
            ma[4*q+0]=u.x; ma[4*q+1]=u.y; ma[4*q+2]=u.z; ma[4*q+3]=u.w;
        }
    }

    // rank-1 folding: delta[i] = b2[i] + sum_j silu(a_j) * W2T[j][i]
    float acc[H];
    #pragma unroll
    for (int k = 0; k < H; ++k) acc[k] = b2[k];

    #pragma unroll 4
    for (int j = 0; j < H; ++j) {
        const float* wj = W1 + j * 2 * H;
        float a = b1[j];
        #pragma unroll
        for (int k = 0; k < H; ++k) a += hr[k] * wj[k];
        #pragma unroll
        for (int k = 0; k < H; ++k) a += ma[k] * wj[32+k];
        float u = silu(a);
        const float* w2j = W2T + j * H;
        #pragma unroll
        for (int k = 0; k < H; ++k) acc[k] += u * w2j[k];
    }

    {
        float4* ho = (float4*)(h_out + (size_t)n * H);
        #pragma unroll
        for (int q = 0; q < H/4; ++q) {
            float4 v;
            v.x = hr[4*q+0] + acc[4*q+0]; v.y = hr[4*q+1] + acc[4*q+1];
            v.z = hr[4*q+2] + acc[4*q+2]; v.w = hr[4*q+3] + acc[4*q+3];
            ho[q] = v;
        }
    }
}

// ---- output: forces = x @ lin_W.T ------------------------------------------
__global__ __launch_bounds__(256) void out_kernel(
    const float* __restrict__ x, const float* __restrict__ lin,
    float* __restrict__ out, int N)
{
    int n = blockIdx.x * blockDim.x + threadIdx.x;
    if (n >= N) return;
    float xr[DOUT];
    const float4* xp = (const float4*)(x + (size_t)n * DOUT);
    #pragma unroll
    for (int q = 0; q < DOUT/4; ++q) {
        float4 v = xp[q];
        xr[4*q+0]=v.x; xr[4*q+1]=v.y; xr[4*q+2]=v.z; xr[4*q+3]=v.w;
    }
    #pragma unroll
    for (int i = 0; i < 3; ++i) {
        float a = 0.0f;
        #pragma unroll
        for (int k = 0; k < DOUT; ++k) a += xr[k] * lin[i*DOUT+k];
        out[(size_t)n*3+i] = a;
    }
}

extern "C" void kernel_launch(void* const* d_in, const int* in_sizes, int n_in,
                              void* d_out, int out_size, void* d_ws, size_t ws_size,
                              hipStream_t stream) {
    const float* node_attrs = (const float*)d_in[0];
    const float* positions  = (const float*)d_in[1];
    const int*   edge_index = (const int*)d_in[2];
    const float* proj_W   = (const float*)d_in[3];
    const float* emb_in_W = (const float*)d_in[4];
    const float* emb_in_b = (const float*)d_in[5];
    const float* edge_W1  = (const float*)d_in[6];
    const float* edge_b1  = (const float*)d_in[7];
    const float* edge_W2  = (const float*)d_in[8];
    const float* edge_b2  = (const float*)d_in[9];
    const float* node_W1  = (const float*)d_in[10];
    const float* node_b1  = (const float*)d_in[11];
    const float* node_W2  = (const float*)d_in[12];
    const float* node_b2  = (const float*)d_in[13];
    const float* coord_W1 = (const float*)d_in[14];
    const float* coord_b1 = (const float*)d_in[15];
    const float* coord_W2 = (const float*)d_in[16];
    const float* lin_W    = (const float*)d_in[19];

    const int N = in_sizes[0] / 3;
    const int E = in_sizes[2] / 2;
    const int* row = edge_index;
    const int* col = edge_index + E;

    // ws: x0,h0,x1,h1 | xsum(16N), magg(32N) | w2t(2048), nw2t(2048) | ints
    float* x0 = (float*)d_ws;
    float* h0 = x0 + (size_t)DOUT * N;
    float* x1 = h0 + (size_t)H * N;
    float* h1 = x1 + (size_t)DOUT * N;
    float* xsum = h1 + (size_t)H * N;
    float* magg = xsum + (size_t)DOUT * N;
    float* w2t  = magg + (size_t)H * N;
    float* nw2t = w2t + 2 * H * H;
    int* deg    = (int*)(nw2t + 2 * H * H);
    int* startv = deg + N;
    int* cursor = startv + N;
    int* ecol   = cursor + N;

    int nB256 = (N + 255) / 256;
    int eB256 = (E + 255) / 256;
    int egBlocks = ((size_t)N * T + BLK - 1) / BLK;

    zero_deg<<<nB256, 256, 0, stream>>>(deg, N);
    hist_kernel<<<eB256, 256, 0, stream>>>(row, deg, E);
    scan_kernel<<<1, 1024, 0, stream>>>(deg, startv, cursor, N);
    scatter_kernel<<<eB256, 256, 0, stream>>>(row, col, cursor, ecol, E);
    transpose_w2<<<(2*H*H + 255)/256, 256, 0, stream>>>(edge_W2, w2t);
    transpose_w2<<<(2*H*H + 255)/256, 256, 0, stream>>>(node_W2, nw2t);

    init_nodes<<<nB256, 256, 0, stream>>>(node_attrs, positions,
                                          proj_W, emb_in_W, emb_in_b, x0, h0, N);

    const float* xi = x0; const float* hi = h0;
    float* xo = x1; float* ho = h1;
    for (int l = 0; l < 2; ++l) {
        edge_kernel<<<egBlocks, BLK, 0, stream>>>(
            startv, deg, ecol, positions, xi, hi,
            edge_W1 + l * (H * 68), edge_b1 + l * H,
            w2t + l * (H * H),      edge_b2 + l * H,
            coord_W1 + l * (H * H), coord_b1 + l * H,
            coord_W2 + l * H,
            xsum, magg, N);
        node_kernel<<<nB256, 256, 0, stream>>>(
            deg, xi, hi, xsum, magg,
            node_W1 + l * (H * 2 * H), node_b1 + l * H,
            nw2t + l * (H * H),        node_b2 + l * H,
            xo, ho, N);
        const float* tx = xi; xi = xo; xo = (float*)tx;
        const float* th = hi; hi = ho; ho = (float*)th;
    }

    out_kernel<<<nB256, 256, 0, stream>>>(xi, lin_W, (float*)d_out, N);
}

// Round 9
// 1592.635 us; speedup vs baseline: 1.0824x; 1.0824x over previous
//
#include <hip/hip_runtime.h>

#define H 32
#define DOUT 16
#define T 32    // threads per node in edge kernel (~1 edge/lane, 25K waves)
#define BLK 256

__device__ __forceinline__ float silu(float v) {
    return v * __builtin_amdgcn_rcpf(1.0f + __expf(-v));
}

// ---- CSR build: deg histogram -> exclusive scan -> scatter reordered col ---
__global__ __launch_bounds__(256) void zero_deg(int* __restrict__ deg, int N) {
    int i = blockIdx.x * blockDim.x + threadIdx.x;
    if (i < N) deg[i] = 0;
}

__global__ __launch_bounds__(256) void hist_kernel(const int* __restrict__ row,
                                                   int* __restrict__ deg, int E) {
    int e = blockIdx.x * blockDim.x + threadIdx.x;
    if (e < E) atomicAdd(&deg[row[e]], 1);
}

// single block of 1024: chunked serial sums + Hillis-Steele scan over partials
__global__ __launch_bounds__(1024) void scan_kernel(const int* __restrict__ deg,
                                                    int* __restrict__ start,
                                                    int* __restrict__ cursor, int N) {
    __shared__ int part[1024];
    int t = threadIdx.x;
    int ch = (N + 1023) >> 10;
    int lo = t * ch, hi = min(lo + ch, N);
    int s = 0;
    for (int i = lo; i < hi; ++i) s += deg[i];
    part[t] = s;
    __syncthreads();
    for (int off = 1; off < 1024; off <<= 1) {
        int v = (t >= off) ? part[t - off] : 0;
        __syncthreads();
        part[t] += v;
        __syncthreads();
    }
    int run = part[t] - s;  // exclusive prefix
    for (int i = lo; i < hi; ++i) {
        start[i] = run; cursor[i] = run;
        run += deg[i];
    }
}

// stores reordered col directly: ecol[slot] = col[e]
__global__ __launch_bounds__(256) void scatter_kernel(const int* __restrict__ row,
                                                      const int* __restrict__ col,
                                                      int* __restrict__ cursor,
                                                      int* __restrict__ ecol, int E) {
    int e = blockIdx.x * blockDim.x + threadIdx.x;
    if (e < E) {
        int p = atomicAdd(&cursor[row[e]], 1);
        ecol[p] = col[e];
    }
}

// ---- transpose edge_W2 (both layers): W2T[l][j][i] = W2[l][i][j] -----------
__global__ __launch_bounds__(256) void transpose_w2(const float* __restrict__ W2,
                                                    float* __restrict__ W2T) {
    int i = blockIdx.x * blockDim.x + threadIdx.x;
    if (i >= 2 * H * H) return;
    int l = i >> 10, r = (i >> 5) & 31, c = i & 31;   // W2[l][r][c]
    W2T[l * H * H + c * H + r] = W2[i];
}

// ---- init: x = pos@projW.T, h = attrs@embW.T + b ---------------------------
__global__ __launch_bounds__(256) void init_nodes(
    const float* __restrict__ node_attrs, const float* __restrict__ positions,
    const float* __restrict__ projW, const float* __restrict__ embW,
    const float* __restrict__ embB,
    float* __restrict__ x, float* __restrict__ h, int N)
{
    int n = blockIdx.x * blockDim.x + threadIdx.x;
    if (n >= N) return;
    float p0 = positions[3*n+0], p1 = positions[3*n+1], p2 = positions[3*n+2];
    #pragma unroll
    for (int i = 0; i < DOUT; ++i)
        x[(size_t)n*DOUT+i] = projW[i*3+0]*p0 + projW[i*3+1]*p1 + projW[i*3+2]*p2;
    float a0 = node_attrs[3*n+0], a1 = node_attrs[3*n+1], a2 = node_attrs[3*n+2];
    #pragma unroll
    for (int j = 0; j < H; ++j)
        h[(size_t)n*H+j] = embB[j] + embW[j*3+0]*a0 + embW[j*3+1]*a1 + embW[j*3+2]*a2;
}

// ---- edge kernel: T=32 threads/node (~1 edge/lane), 25K waves --------------
__global__ __launch_bounds__(BLK) void edge_kernel(
    const int* __restrict__ start, const int* __restrict__ deg,
    const int* __restrict__ ecol,
    const float* __restrict__ positions,
    const float* __restrict__ x_in, const float* __restrict__ h_in,
    const float* __restrict__ eW1, const float* __restrict__ eb1,
    const float* __restrict__ W2T, const float* __restrict__ eb2,
    const float* __restrict__ cW1, const float* __restrict__ cb1,
    const float* __restrict__ cW2,
    float* __restrict__ xsum, float* __restrict__ magg, int N)
{
    int gid = blockIdx.x * BLK + threadIdx.x;
    int n = gid / T, sub = gid & (T - 1);
    if (n >= N) return;

    int s0 = start[n], dg = deg[n];

    float xr[DOUT];
    {
        const float4* xp = (const float4*)(x_in + (size_t)n * DOUT);
        #pragma unroll
        for (int q = 0; q < DOUT/4; ++q) {
            float4 v = xp[q];
            xr[4*q+0]=v.x; xr[4*q+1]=v.y; xr[4*q+2]=v.z; xr[4*q+3]=v.w;
        }
    }
    float hr[H];
    {
        const float4* hp = (const float4*)(h_in + (size_t)n * H);
        #pragma unroll
        for (int q = 0; q < H/4; ++q) {
            float4 v = hp[q];
            hr[4*q+0]=v.x; hr[4*q+1]=v.y; hr[4*q+2]=v.z; hr[4*q+3]=v.w;
        }
    }
    float pr0 = positions[3*n+0], pr1 = positions[3*n+1], pr2 = positions[3*n+2];

    float xs[DOUT];
    #pragma unroll
    for (int i = 0; i < DOUT; ++i) xs[i] = 0.0f;
    float ma[H];
    #pragma unroll
    for (int k = 0; k < H; ++k) ma[k] = 0.0f;

    for (int i = sub; i < dg; i += T) {
        int c = ecol[s0 + i];

        float cd[DOUT];
        {
            const float4* xc = (const float4*)(x_in + (size_t)c * DOUT);
            #pragma unroll
            for (int q = 0; q < DOUT/4; ++q) {
                float4 v = xc[q];
                cd[4*q+0] = xr[4*q+0]-v.x; cd[4*q+1] = xr[4*q+1]-v.y;
                cd[4*q+2] = xr[4*q+2]-v.z; cd[4*q+3] = xr[4*q+3]-v.w;
            }
        }
        float radial = 0.0f;
        #pragma unroll
        for (int i2 = 0; i2 < DOUT; ++i2) radial += cd[i2] * cd[i2];

        float hc[H];
        {
            const float4* hp = (const float4*)(h_in + (size_t)c * H);
            #pragma unroll
            for (int q = 0; q < H/4; ++q) {
                float4 v = hp[q];
                hc[4*q+0]=v.x; hc[4*q+1]=v.y; hc[4*q+2]=v.z; hc[4*q+3]=v.w;
            }
        }
        float ea0 = pr0 - positions[3*c+0];
        float ea1 = pr1 - positions[3*c+1];
        float ea2 = pr2 - positions[3*c+2];

        // MLP2 accumulators start at bias; MLP1 neuron j does rank-1 update
        float acc[H];
        #pragma unroll
        for (int k = 0; k < H; ++k) acc[k] = eb2[k];

        #pragma unroll 4
        for (int j = 0; j < H; ++j) {
            const float* wj = eW1 + j * 68;
            float a = eb1[j];
            #pragma unroll
            for (int k = 0; k < H; ++k) a += hr[k] * wj[k];
            #pragma unroll
            for (int k = 0; k < H; ++k) a += hc[k] * wj[32+k];
            a += radial * wj[64] + ea0 * wj[65] + ea1 * wj[66] + ea2 * wj[67];
            float m1j = silu(a);
            const float* w2j = W2T + j * H;   // column j of W2
            #pragma unroll
            for (int k = 0; k < H; ++k) acc[k] += m1j * w2j[k];
        }

        // m2 = silu(acc); aggregate
        #pragma unroll
        for (int k = 0; k < H; ++k) {
            float v = silu(acc[k]);
            acc[k] = v;
            ma[k] += v;
        }

        // coord MLP: 32 -> 32 silu -> 1
        float cm = 0.0f;
        #pragma unroll 4
        for (int j = 0; j < H; ++j) {
            const float* wj = cW1 + j * H;
            float a = cb1[j];
            #pragma unroll
            for (int k = 0; k < H; ++k) a += acc[k] * wj[k];
            cm += silu(a) * cW2[j];
        }

        #pragma unroll
        for (int i2 = 0; i2 < DOUT; ++i2) xs[i2] += cd[i2] * cm;
    }

    // reduce partials across the T adjacent lanes of this node (same wave)
    #pragma unroll
    for (int m = 1; m < T; m <<= 1) {
        #pragma unroll
        for (int k = 0; k < H; ++k) ma[k] += __shfl_xor(ma[k], m, 64);
        #pragma unroll
        for (int i = 0; i < DOUT; ++i) xs[i] += __shfl_xor(xs[i], m, 64);
    }

    if (sub == 0) {
        float4* mo = (float4*)(magg + (size_t)n * H);
        #pragma unroll
        for (int q = 0; q < H/4; ++q) {
            float4 v; v.x=ma[4*q+0]; v.y=ma[4*q+1]; v.z=ma[4*q+2]; v.w=ma[4*q+3];
            mo[q] = v;
        }
        float4* xo = (float4*)(xsum + (size_t)n * DOUT);
        #pragma unroll
        for (int q = 0; q < DOUT/4; ++q) {
            float4 v; v.x=xs[4*q+0]; v.y=xs[4*q+1]; v.z=xs[4*q+2]; v.w=xs[4*q+3];
            xo[q] = v;
        }
    }
}

// ---- node update: x += xsum/max(deg,1); h += MLP([h, m_agg]) ---------------
__global__ __launch_bounds__(256) void node_kernel(
    const int* __restrict__ deg,
    const float* __restrict__ x_in, const float* __restrict__ h_in,
    const float* __restrict__ xsum, const float* __restrict__ magg,
    const float* __restrict__ W1, const float* __restrict__ b1,
    const float* __restrict__ W2T, const float* __restrict__ b2,
    float* __restrict__ x_out, float* __restrict__ h_out, int N)
{
    int n = blockIdx.x * blockDim.x + threadIdx.x;
    if (n >= N) return;

    float inv = __builtin_amdgcn_rcpf(fmaxf((float)deg[n], 1.0f));
    {
        const float4* xi = (const float4*)(x_in + (size_t)n * DOUT);
        const float4* xa = (const float4*)(xsum + (size_t)n * DOUT);
        float4* xo = (float4*)(x_out + (size_t)n * DOUT);
        #pragma unroll
        for (int q = 0; q < DOUT/4; ++q) {
            float4 a = xi[q], b = xa[q];
            float4 v; v.x=a.x+b.x*inv; v.y=a.y+b.y*inv; v.z=a.z+b.z*inv; v.w=a.w+b.w*inv;
            xo[q] = v;
        }
    }

    float hr[H], ma[H];
    {
        const float4* hp = (const float4*)(h_in + (size_t)n * H);
        const float4* mp = (const float4*)(magg + (size_t)n * H);
        #pragma unroll
        for (int q = 0; q < H/4; ++q) {
            float4 v = hp[q];
            hr[4*q+0]=v.x; hr[4*q+1]=v.y; hr[4*q+2]=v.z; hr[4*q+3]=v.w;
            float4 u = mp[q];
            ma[4*q+0]=u.x; ma[4*q+1]=u.y; ma[4*q+2]=u.z; ma[4*q+3]=u.w;
        }
    }

    // rank-1 folding: delta[i] = b2[i] + sum_j silu(a_j) * W2T[j][i]
    float acc[H];
    #pragma unroll
    for (int k = 0; k < H; ++k) acc[k] = b2[k];

    #pragma unroll 4
    for (int j = 0; j < H; ++j) {
        const float* wj = W1 + j * 2 * H;
        float a = b1[j];
        #pragma unroll
        for (int k = 0; k < H; ++k) a += hr[k] * wj[k];
        #pragma unroll
        for (int k = 0; k < H; ++k) a += ma[k] * wj[32+k];
        float u = silu(a);
        const float* w2j = W2T + j * H;
        #pragma unroll
        for (int k = 0; k < H; ++k) acc[k] += u * w2j[k];
    }

    {
        float4* ho = (float4*)(h_out + (size_t)n * H);
        #pragma unroll
        for (int q = 0; q < H/4; ++q) {
            float4 v;
            v.x = hr[4*q+0] + acc[4*q+0]; v.y = hr[4*q+1] + acc[4*q+1];
            v.z = hr[4*q+2] + acc[4*q+2]; v.w = hr[4*q+3] + acc[4*q+3];
            ho[q] = v;
        }
    }
}

// ---- output: forces = x @ lin_W.T ------------------------------------------
__global__ __launch_bounds__(256) void out_kernel(
    const float* __restrict__ x, const float* __restrict__ lin,
    float* __restrict__ out, int N)
{
    int n = blockIdx.x * blockDim.x + threadIdx.x;
    if (n >= N) return;
    float xr[DOUT];
    const float4* xp = (const float4*)(x + (size_t)n * DOUT);
    #pragma unroll
    for (int q = 0; q < DOUT/4; ++q) {
        float4 v = xp[q];
        xr[4*q+0]=v.x; xr[4*q+1]=v.y; xr[4*q+2]=v.z; xr[4*q+3]=v.w;
    }
    #pragma unroll
    for (int i = 0; i < 3; ++i) {
        float a = 0.0f;
        #pragma unroll
        for (int k = 0; k < DOUT; ++k) a += xr[k] * lin[i*DOUT+k];
        out[(size_t)n*3+i] = a;
    }
}

extern "C" void kernel_launch(void* const* d_in, const int* in_sizes, int n_in,
                              void* d_out, int out_size, void* d_ws, size_t ws_size,
                              hipStream_t stream) {
    const float* node_attrs = (const float*)d_in[0];
    const float* positions  = (const float*)d_in[1];
    const int*   edge_index = (const int*)d_in[2];
    const float* proj_W   = (const float*)d_in[3];
    const float* emb_in_W = (const float*)d_in[4];
    const float* emb_in_b = (const float*)d_in[5];
    const float* edge_W1  = (const float*)d_in[6];
    const float* edge_b1  = (const float*)d_in[7];
    const float* edge_W2  = (const float*)d_in[8];
    const float* edge_b2  = (const float*)d_in[9];
    const float* node_W1  = (const float*)d_in[10];
    const float* node_b1  = (const float*)d_in[11];
    const float* node_W2  = (const float*)d_in[12];
    const float* node_b2  = (const float*)d_in[13];
    const float* coord_W1 = (const float*)d_in[14];
    const float* coord_b1 = (const float*)d_in[15];
    const float* coord_W2 = (const float*)d_in[16];
    const float* lin_W    = (const float*)d_in[19];

    const int N = in_sizes[0] / 3;
    const int E = in_sizes[2] / 2;
    const int* row = edge_index;
    const int* col = edge_index + E;

    // ws: x0,h0,x1,h1 | xsum(16N), magg(32N) | w2t(2048), nw2t(2048) | ints
    float* x0 = (float*)d_ws;
    float* h0 = x0 + (size_t)DOUT * N;
    float* x1 = h0 + (size_t)H * N;
    float* h1 = x1 + (size_t)DOUT * N;
    float* xsum = h1 + (size_t)H * N;
    float* magg = xsum + (size_t)DOUT * N;
    float* w2t  = magg + (size_t)H * N;
    float* nw2t = w2t + 2 * H * H;
    int* deg    = (int*)(nw2t + 2 * H * H);
    int* startv = deg + N;
    int* cursor = startv + N;
    int* ecol   = cursor + N;

    int nB256 = (N + 255) / 256;
    int eB256 = (E + 255) / 256;
    int egBlocks = ((size_t)N * T + BLK - 1) / BLK;

    zero_deg<<<nB256, 256, 0, stream>>>(deg, N);
    hist_kernel<<<eB256, 256, 0, stream>>>(row, deg, E);
    scan_kernel<<<1, 1024, 0, stream>>>(deg, startv, cursor, N);
    scatter_kernel<<<eB256, 256, 0, stream>>>(row, col, cursor, ecol, E);
    transpose_w2<<<(2*H*H + 255)/256, 256, 0, stream>>>(edge_W2, w2t);
    transpose_w2<<<(2*H*H + 255)/256, 256, 0, stream>>>(node_W2, nw2t);

    init_nodes<<<nB256, 256, 0, stream>>>(node_attrs, positions,
                                          proj_W, emb_in_W, emb_in_b, x0, h0, N);

    const float* xi = x0; const float* hi = h0;
    float* xo = x1; float* ho = h1;
    for (int l = 0; l < 2; ++l) {
        edge_kernel<<<egBlocks, BLK, 0, stream>>>(
            startv, deg, ecol, positions, xi, hi,
            edge_W1 + l * (H * 68), edge_b1 + l * H,
            w2t + l * (H * H),      edge_b2 + l * H,
            coord_W1 + l * (H * H), coord_b1 + l * H,
            coord_W2 + l * H,
            xsum, magg, N);
        node_kernel<<<nB256, 256, 0, stream>>>(
            deg, xi, hi, xsum, magg,
            node_W1 + l * (H * 2 * H), node_b1 + l * H,
            nw2t + l * (H * H),        node_b2 + l * H,
            xo, ho, N);
        const float* tx = xi; xi = xo; xo = (float*)tx;
        const float* th = hi; hi = ho; ho = (float*)th;
    }

    out_kernel<<<nB256, 256, 0, stream>>>(xi, lin_W, (float*)d_out, N);
}

// Round 10
// 859.812 us; speedup vs baseline: 2.0049x; 1.8523x over previous
//
#include <hip/hip_runtime.h>

#define H 32
#define DOUT 16
#define APITCH 104   // bf16 elems per A_in row (208B, 16B-multiple, 2-way-conflict-free)

typedef unsigned short ushort_t;
typedef __attribute__((ext_vector_type(8))) short bf16x8;
typedef __attribute__((ext_vector_type(4))) float f32x4;

__device__ __forceinline__ float silu(float v) {
    return v * __builtin_amdgcn_rcpf(1.0f + __expf(-v));
}
__device__ __forceinline__ ushort_t f2bf(float f) {
    unsigned int u = __float_as_uint(f);
    unsigned int r = (u + 0x7FFFu + ((u >> 16) & 1u)) >> 16;  // RNE
    return (ushort_t)r;
}
__device__ __forceinline__ float bf2f(ushort_t h) {
    return __uint_as_float(((unsigned int)h) << 16);
}

// ---- CSR build -------------------------------------------------------------
__global__ __launch_bounds__(256) void zero_deg(int* __restrict__ deg, int N) {
    int i = blockIdx.x * blockDim.x + threadIdx.x;
    if (i < N) deg[i] = 0;
}

__global__ __launch_bounds__(256) void hist_kernel(const int* __restrict__ row,
                                                   int* __restrict__ deg, int E) {
    int e = blockIdx.x * blockDim.x + threadIdx.x;
    if (e < E) atomicAdd(&deg[row[e]], 1);
}

__global__ __launch_bounds__(1024) void scan_kernel(const int* __restrict__ deg,
                                                    int* __restrict__ start,
                                                    int* __restrict__ cursor, int N) {
    __shared__ int part[1024];
    int t = threadIdx.x;
    int ch = (N + 1023) >> 10;
    int lo = t * ch, hi = min(lo + ch, N);
    int s = 0;
    for (int i = lo; i < hi; ++i) s += deg[i];
    part[t] = s;
    __syncthreads();
    for (int off = 1; off < 1024; off <<= 1) {
        int v = (t >= off) ? part[t - off] : 0;
        __syncthreads();
        part[t] += v;
        __syncthreads();
    }
    int run = part[t] - s;
    for (int i = lo; i < hi; ++i) {
        start[i] = run; cursor[i] = run;
        run += deg[i];
    }
}

__global__ __launch_bounds__(256) void scatter_kernel(const int* __restrict__ row,
                                                      const int* __restrict__ col,
                                                      int* __restrict__ cursor,
                                                      int* __restrict__ ecol,
                                                      int* __restrict__ erow, int E) {
    int e = blockIdx.x * blockDim.x + threadIdx.x;
    if (e < E) {
        int r = row[e];
        int p = atomicAdd(&cursor[r], 1);
        ecol[p] = col[e];
        erow[p] = r;
    }
}

// ---- pack weights into MFMA B-fragment order (bf16) ------------------------
// B-frag: lane holds B[k = 32*kc + 8*(lane>>4) + j][n = 16*nt + (lane&15)], j in [0,8)
// W1p[k][n] = edge_W1[n][k] (k<68), = edge_b1[n] (k==68, pairs with e_in[68]=1), else 0
__global__ __launch_bounds__(256) void pack_weights(
    const float* __restrict__ eW1, const float* __restrict__ eb1,
    const float* __restrict__ eW2, const float* __restrict__ cW1,
    ushort_t* __restrict__ W1B, ushort_t* __restrict__ W2B,
    ushort_t* __restrict__ CW1B)
{
    int t = blockIdx.x * 256 + threadIdx.x;
    if (t < 6144) {  // 2 layers * 3 kc * 2 nt * 64 lanes * 8
        int j = t & 7; int r1 = t >> 3;
        int lane = r1 & 63; int r2 = r1 >> 6;
        int nt = r2 & 1; int r3 = r2 >> 1;
        int kc = r3 % 3; int l = r3 / 3;
        int n = 16 * nt + (lane & 15);
        int k = 32 * kc + 8 * (lane >> 4) + j;
        float v = 0.0f;
        if (k < 68) v = eW1[(l * 32 + n) * 68 + k];
        else if (k == 68) v = eb1[l * 32 + n];
        W1B[t] = f2bf(v);
    }
    if (t < 2048) {  // 2 layers * 2 nt * 64 * 8 (K=32 single chunk)
        int j = t & 7; int lane = (t >> 3) & 63;
        int nt = (t >> 9) & 1; int l = t >> 10;
        int n = 16 * nt + (lane & 15);
        int k = 8 * (lane >> 4) + j;
        W2B[t]  = f2bf(eW2[(l * 32 + n) * 32 + k]);
        CW1B[t] = f2bf(cW1[(l * 32 + n) * 32 + k]);
    }
}

// ---- transpose node_W2 for scalar node kernel ------------------------------
__global__ __launch_bounds__(256) void transpose_w2(const float* __restrict__ W2,
                                                    float* __restrict__ W2T) {
    int i = blockIdx.x * blockDim.x + threadIdx.x;
    if (i >= 2 * H * H) return;
    int l = i >> 10, r = (i >> 5) & 31, c = i & 31;
    W2T[l * H * H + c * H + r] = W2[i];
}

// ---- init ------------------------------------------------------------------
__global__ __launch_bounds__(256) void init_nodes(
    const float* __restrict__ node_attrs, const float* __restrict__ positions,
    const float* __restrict__ projW, const float* __restrict__ embW,
    const float* __restrict__ embB,
    float* __restrict__ x, float* __restrict__ h, int N)
{
    int n = blockIdx.x * blockDim.x + threadIdx.x;
    if (n >= N) return;
    float p0 = positions[3*n+0], p1 = positions[3*n+1], p2 = positions[3*n+2];
    #pragma unroll
    for (int i = 0; i < DOUT; ++i)
        x[(size_t)n*DOUT+i] = projW[i*3+0]*p0 + projW[i*3+1]*p1 + projW[i*3+2]*p2;
    float a0 = node_attrs[3*n+0], a1 = node_attrs[3*n+1], a2 = node_attrs[3*n+2];
    #pragma unroll
    for (int j = 0; j < H; ++j)
        h[(size_t)n*H+j] = embB[j] + embW[j*3+0]*a0 + embW[j*3+1]*a1 + embW[j*3+2]*a2;
}

__global__ __launch_bounds__(256) void zero_acc(float* __restrict__ xsum,
                                                float* __restrict__ magg, int N) {
    int i = blockIdx.x * blockDim.x + threadIdx.x;
    if (i < N * DOUT) xsum[i] = 0.0f;
    if (i < N * H) magg[i] = 0.0f;
}

// ---- MFMA edge kernel: 64 edges per block, 4 waves x 16-edge M-tiles -------
__global__ __launch_bounds__(256) void edge_mfma(
    const int* __restrict__ erow_g, const int* __restrict__ ecol_g,
    const float* __restrict__ positions,
    const float* __restrict__ x_in, const float* __restrict__ h_in,
    const ushort_t* __restrict__ W1B, const ushort_t* __restrict__ W2B,
    const ushort_t* __restrict__ CW1B,
    const float* __restrict__ eb2, const float* __restrict__ cb1,
    const float* __restrict__ cw2,
    float* __restrict__ xsum, float* __restrict__ magg, int E)
{
    __shared__ __align__(16) ushort_t Ain[64 * APITCH];   // e_in tile, bf16
    __shared__ __align__(16) float    CDs[64 * 20];       // coord_diff fp32
    __shared__ __align__(16) ushort_t M1s[4 * 16 * 40];   // per-wave m1
    __shared__ __align__(16) ushort_t M2s[4 * 16 * 40];   // per-wave m2
    __shared__ float CMs[64];
    __shared__ int ERO[64];
    __shared__ int RSTART[65];
    __shared__ int RNODE[64];
    __shared__ int NRUN;

    const int tid = threadIdx.x;
    const int t0 = blockIdx.x * 64;
    const int ntile = min(64, E - t0);
    const int lane = tid & 63;
    const int w = tid >> 6;
    const int nidx = lane & 15;
    const int q = lane >> 4;

    // persistent weight fragments (40 VGPR) + per-lane bias/cw2 scalars
    bf16x8 w1f[3][2], w2f[2], cwf[2];
    #pragma unroll
    for (int kc = 0; kc < 3; ++kc)
        #pragma unroll
        for (int nt = 0; nt < 2; ++nt)
            w1f[kc][nt] = *(const bf16x8*)(W1B + ((size_t)((kc*2+nt)*64 + lane)) * 8);
    #pragma unroll
    for (int nt = 0; nt < 2; ++nt) {
        w2f[nt] = *(const bf16x8*)(W2B + (size_t)(nt*64 + lane) * 8);
        cwf[nt] = *(const bf16x8*)(CW1B + (size_t)(nt*64 + lane) * 8);
    }
    float eb2v0 = eb2[nidx], eb2v1 = eb2[16 + nidx];
    float cb1v0 = cb1[nidx], cb1v1 = cb1[16 + nidx];
    float cw2v0 = cw2[nidx], cw2v1 = cw2[16 + nidx];

    // ---- Phase A0: zero K-tail, stage h (bf16), compute cd/radial ----------
    for (int idx = tid; idx < 64 * 5; idx += 256) {   // cols 64..103 zeroed
        int rr = idx / 5, seg = idx % 5;
        *(uint4*)((char*)Ain + rr * 208 + 128 + seg * 16) = make_uint4(0,0,0,0);
    }
    {   // 4 threads per edge: parts 0,1 = h[row] halves; 2,3 = h[col] halves
        int e = tid >> 2, part = tid & 3;
        int s = t0 + e;
        unsigned int u[8] = {0,0,0,0,0,0,0,0};
        if (s < E) {
            int node = (part < 2) ? erow_g[s] : ecol_g[s];
            const float4* hp = (const float4*)(h_in + (size_t)node * H + (size_t)(part & 1) * 16);
            #pragma unroll
            for (int qq = 0; qq < 4; ++qq) {
                float4 v = hp[qq];
                u[2*qq]   = (unsigned)f2bf(v.x) | ((unsigned)f2bf(v.y) << 16);
                u[2*qq+1] = (unsigned)f2bf(v.z) | ((unsigned)f2bf(v.w) << 16);
            }
        }
        uint4* dst = (uint4*)((char*)Ain + e * 208 + part * 32);
        dst[0] = make_uint4(u[0], u[1], u[2], u[3]);
        dst[1] = make_uint4(u[4], u[5], u[6], u[7]);
    }
    float radial = 0.0f, ea0 = 0.0f, ea1 = 0.0f, ea2 = 0.0f;
    if (tid < 64) {
        int s = t0 + tid;
        if (s < E) {
            int r = erow_g[s], c = ecol_g[s];
            ERO[tid] = r;
            const float4* xr = (const float4*)(x_in + (size_t)r * DOUT);
            const float4* xc = (const float4*)(x_in + (size_t)c * DOUT);
            #pragma unroll
            for (int qq = 0; qq < 4; ++qq) {
                float4 a = xr[qq], b = xc[qq];
                float4 d;
                d.x = a.x - b.x; d.y = a.y - b.y; d.z = a.z - b.z; d.w = a.w - b.w;
                *(float4*)(CDs + tid * 20 + qq * 4) = d;
                radial += d.x*d.x + d.y*d.y + d.z*d.z + d.w*d.w;
            }
            ea0 = positions[3*r+0] - positions[3*c+0];
            ea1 = positions[3*r+1] - positions[3*c+1];
            ea2 = positions[3*r+2] - positions[3*c+2];
        } else {
            ERO[tid] = -1;
        }
    }
    __syncthreads();
    // ---- Phase A1: radial/ea/bias-one into cols 64..68 ---------------------
    if (tid < 64 && t0 + tid < E) {
        ushort_t* rowp = Ain + tid * APITCH;
        rowp[64] = f2bf(radial);
        rowp[65] = f2bf(ea0); rowp[66] = f2bf(ea1); rowp[67] = f2bf(ea2);
        rowp[68] = 0x3F80;  // bf16(1.0) -> pairs with baked eb1 row
    }
    __syncthreads();

    // ---- Phase B: MLP1 (68->32) via 6 MFMAs, K=96 --------------------------
    const int mrow = 16 * w + nidx;          // local edge row for A-frags
    bf16x8 af0 = *(const bf16x8*)(Ain + mrow * APITCH + 0  + 8 * q);
    bf16x8 af1 = *(const bf16x8*)(Ain + mrow * APITCH + 32 + 8 * q);
    bf16x8 af2 = *(const bf16x8*)(Ain + mrow * APITCH + 64 + 8 * q);
    f32x4 z4 = {0.0f, 0.0f, 0.0f, 0.0f};
    f32x4 acc0 = z4, acc1 = z4;
    acc0 = __builtin_amdgcn_mfma_f32_16x16x32_bf16(af0, w1f[0][0], acc0, 0, 0, 0);
    acc0 = __builtin_amdgcn_mfma_f32_16x16x32_bf16(af1, w1f[1][0], acc0, 0, 0, 0);
    acc0 = __builtin_amdgcn_mfma_f32_16x16x32_bf16(af2, w1f[2][0], acc0, 0, 0, 0);
    acc1 = __builtin_amdgcn_mfma_f32_16x16x32_bf16(af0, w1f[0][1], acc1, 0, 0, 0);
    acc1 = __builtin_amdgcn_mfma_f32_16x16x32_bf16(af1, w1f[1][1], acc1, 0, 0, 0);
    acc1 = __builtin_amdgcn_mfma_f32_16x16x32_bf16(af2, w1f[2][1], acc1, 0, 0, 0);

    ushort_t* m1w = M1s + w * 16 * 40;
    #pragma unroll
    for (int r = 0; r < 4; ++r) {           // C layout: row=4q+r, col=nidx(+16)
        m1w[(4*q + r) * 40 + nidx]      = f2bf(silu(acc0[r]));
        m1w[(4*q + r) * 40 + 16 + nidx] = f2bf(silu(acc1[r]));
    }

    // ---- Phase C: MLP2 (32->32), bias in epilogue --------------------------
    bf16x8 a2 = *(const bf16x8*)(m1w + nidx * 40 + 8 * q);
    f32x4 b0 = __builtin_amdgcn_mfma_f32_16x16x32_bf16(a2, w2f[0], z4, 0, 0, 0);
    f32x4 b1 = __builtin_amdgcn_mfma_f32_16x16x32_bf16(a2, w2f[1], z4, 0, 0, 0);
    ushort_t* m2w = M2s + w * 16 * 40;
    #pragma unroll
    for (int r = 0; r < 4; ++r) {
        m2w[(4*q + r) * 40 + nidx]      = f2bf(silu(b0[r] + eb2v0));
        m2w[(4*q + r) * 40 + 16 + nidx] = f2bf(silu(b1[r] + eb2v1));
    }

    // ---- Phase D: coord MLP (32->32 silu -> dot cW2) -----------------------
    bf16x8 a3 = *(const bf16x8*)(m2w + nidx * 40 + 8 * q);
    f32x4 c0 = __builtin_amdgcn_mfma_f32_16x16x32_bf16(a3, cwf[0], z4, 0, 0, 0);
    f32x4 c1 = __builtin_amdgcn_mfma_f32_16x16x32_bf16(a3, cwf[1], z4, 0, 0, 0);
    float p[4];
    #pragma unroll
    for (int r = 0; r < 4; ++r)
        p[r] = silu(c0[r] + cb1v0) * cw2v0 + silu(c1[r] + cb1v1) * cw2v1;
    #pragma unroll
    for (int m = 1; m < 16; m <<= 1) {
        #pragma unroll
        for (int r = 0; r < 4; ++r) p[r] += __shfl_xor(p[r], m, 64);
    }
    if (nidx == 0) {
        #pragma unroll
        for (int r = 0; r < 4; ++r) CMs[16*w + 4*q + r] = p[r];
    }
    __syncthreads();

    // ---- Phase E: run detection (ballot) + segmented sums + few atomics ----
    if (tid < 64) {
        bool f = (tid < ntile) && (tid == 0 || ERO[tid] != ERO[tid - 1]);
        unsigned long long mask = __ballot(f);
        if (f) {
            int rank = (int)__popcll(mask & ((1ull << tid) - 1ull));
            RSTART[rank] = tid;
            RNODE[rank] = ERO[tid];
        }
        if (tid == 0) {
            int nr = (int)__popcll(mask);
            NRUN = nr;
            RSTART[nr] = ntile;   // sentinel
        }
    }
    __syncthreads();
    int nrun = NRUN;
    for (int idx = tid; idx < nrun * 48; idx += 256) {
        int k = idx / 48, d = idx - k * 48;
        int s = RSTART[k], en = RSTART[k + 1];
        int node = RNODE[k];
        float sum = 0.0f;
        if (d < 32) {
            for (int e = s; e < en; ++e)
                sum += bf2f(M2s[(e >> 4) * 640 + (e & 15) * 40 + d]);
            unsafeAtomicAdd(&magg[(size_t)node * H + d], sum);
        } else {
            int dd = d - 32;
            for (int e = s; e < en; ++e)
                sum += CDs[e * 20 + dd] * CMs[e];
            unsafeAtomicAdd(&xsum[(size_t)node * DOUT + dd], sum);
        }
    }
}

// ---- node update (scalar, unchanged) ---------------------------------------
__global__ __launch_bounds__(256) void node_kernel(
    const int* __restrict__ deg,
    const float* __restrict__ x_in, const float* __restrict__ h_in,
    const float* __restrict__ xsum, const float* __restrict__ magg,
    const float* __restrict__ W1, const float* __restrict__ b1,
    const float* __restrict__ W2T, const float* __restrict__ b2,
    float* __restrict__ x_out, float* __restrict__ h_out, int N)
{
    int n = blockIdx.x * blockDim.x + threadIdx.x;
    if (n >= N) return;

    float inv = __builtin_amdgcn_rcpf(fmaxf((float)deg[n], 1.0f));
    {
        const float4* xi = (const float4*)(x_in + (size_t)n * DOUT);
        const float4* xa = (const float4*)(xsum + (size_t)n * DOUT);
        float4* xo = (float4*)(x_out + (size_t)n * DOUT);
        #pragma unroll
        for (int qq = 0; qq < DOUT/4; ++qq) {
            float4 a = xi[qq], b = xa[qq];
            float4 v; v.x=a.x+b.x*inv; v.y=a.y+b.y*inv; v.z=a.z+b.z*inv; v.w=a.w+b.w*inv;
            xo[qq] = v;
        }
    }

    float hr[H], ma[H];
    {
        const float4* hp = (const float4*)(h_in + (size_t)n * H);
        const float4* mp = (const float4*)(magg + (size_t)n * H);
        #pragma unroll
        for (int qq = 0; qq < H/4; ++qq) {
            float4 v = hp[qq];
            hr[4*qq+0]=v.x; hr[4*qq+1]=v.y; hr[4*qq+2]=v.z; hr[4*qq+3]=v.w;
            float4 u = mp[qq];
            ma[4*qq+0]=u.x; ma[4*qq+1]=u.y; ma[4*qq+2]=u.z; ma[4*qq+3]=u.w;
        }
    }

    float acc[H];
    #pragma unroll
    for (int k = 0; k < H; ++k) acc[k] = b2[k];

    #pragma unroll 4
    for (int j = 0; j < H; ++j) {
        const float* wj = W1 + j * 2 * H;
        float a = b1[j];
        #pragma unroll
        for (int k = 0; k < H; ++k) a += hr[k] * wj[k];
        #pragma unroll
        for (int k = 0; k < H; ++k) a += ma[k] * wj[32+k];
        float u = silu(a);
        const float* w2j = W2T + j * H;
        #pragma unroll
        for (int k = 0; k < H; ++k) acc[k] += u * w2j[k];
    }

    {
        float4* ho = (float4*)(h_out + (size_t)n * H);
        #pragma unroll
        for (int qq = 0; qq < H/4; ++qq) {
            float4 v;
            v.x = hr[4*qq+0] + acc[4*qq+0]; v.y = hr[4*qq+1] + acc[4*qq+1];
            v.z = hr[4*qq+2] + acc[4*qq+2]; v.w = hr[4*qq+3] + acc[4*qq+3];
            ho[qq] = v;
        }
    }
}

// ---- output ----------------------------------------------------------------
__global__ __launch_bounds__(256) void out_kernel(
    const float* __restrict__ x, const float* __restrict__ lin,
    float* __restrict__ out, int N)
{
    int n = blockIdx.x * blockDim.x + threadIdx.x;
    if (n >= N) return;
    float xr[DOUT];
    const float4* xp = (const float4*)(x + (size_t)n * DOUT);
    #pragma unroll
    for (int qq = 0; qq < DOUT/4; ++qq) {
        float4 v = xp[qq];
        xr[4*qq+0]=v.x; xr[4*qq+1]=v.y; xr[4*qq+2]=v.z; xr[4*qq+3]=v.w;
    }
    #pragma unroll
    for (int i = 0; i < 3; ++i) {
        float a = 0.0f;
        #pragma unroll
        for (int k = 0; k < DOUT; ++k) a += xr[k] * lin[i*DOUT+k];
        out[(size_t)n*3+i] = a;
    }
}

extern "C" void kernel_launch(void* const* d_in, const int* in_sizes, int n_in,
                              void* d_out, int out_size, void* d_ws, size_t ws_size,
                              hipStream_t stream) {
    const float* node_attrs = (const float*)d_in[0];
    const float* positions  = (const float*)d_in[1];
    const int*   edge_index = (const int*)d_in[2];
    const float* proj_W   = (const float*)d_in[3];
    const float* emb_in_W = (const float*)d_in[4];
    const float* emb_in_b = (const float*)d_in[5];
    const float* edge_W1  = (const float*)d_in[6];
    const float* edge_b1  = (const float*)d_in[7];
    const float* edge_W2  = (const float*)d_in[8];
    const float* edge_b2  = (const float*)d_in[9];
    const float* node_W1  = (const float*)d_in[10];
    const float* node_b1  = (const float*)d_in[11];
    const float* node_W2  = (const float*)d_in[12];
    const float* node_b2  = (const float*)d_in[13];
    const float* coord_W1 = (const float*)d_in[14];
    const float* coord_b1 = (const float*)d_in[15];
    const float* coord_W2 = (const float*)d_in[16];
    const float* lin_W    = (const float*)d_in[19];

    const int N = in_sizes[0] / 3;
    const int E = in_sizes[2] / 2;
    const int* row = edge_index;
    const int* col = edge_index + E;

    // ws: x0,h0,x1,h1 | xsum(16N), magg(32N) | nw2t(2048) | packed bf16 | ints
    float* x0 = (float*)d_ws;
    float* h0 = x0 + (size_t)DOUT * N;
    float* x1 = h0 + (size_t)H * N;
    float* h1 = x1 + (size_t)DOUT * N;
    float* xsum = h1 + (size_t)H * N;
    float* magg = xsum + (size_t)DOUT * N;
    float* nw2t = magg + (size_t)H * N;
    ushort_t* W1B  = (ushort_t*)(nw2t + 2 * H * H);   // 6144
    ushort_t* W2B  = W1B + 6144;                      // 2048
    ushort_t* CW1B = W2B + 2048;                      // 2048
    int* deg    = (int*)(CW1B + 2048);
    int* startv = deg + N;
    int* cursor = startv + N;
    int* ecol   = cursor + N;
    int* erow   = ecol + E;

    int nB256 = (N + 255) / 256;
    int eB256 = (E + 255) / 256;
    int tBlocks = (E + 63) / 64;

    zero_deg<<<nB256, 256, 0, stream>>>(deg, N);
    hist_kernel<<<eB256, 256, 0, stream>>>(row, deg, E);
    scan_kernel<<<1, 1024, 0, stream>>>(deg, startv, cursor, N);
    scatter_kernel<<<eB256, 256, 0, stream>>>(row, col, cursor, ecol, erow, E);
    pack_weights<<<24, 256, 0, stream>>>(edge_W1, edge_b1, edge_W2, coord_W1,
                                         W1B, W2B, CW1B);
    transpose_w2<<<(2*H*H + 255)/256, 256, 0, stream>>>(node_W2, nw2t);

    init_nodes<<<nB256, 256, 0, stream>>>(node_attrs, positions,
                                          proj_W, emb_in_W, emb_in_b, x0, h0, N);

    const float* xi = x0; const float* hi = h0;
    float* xo = x1; float* ho = h1;
    for (int l = 0; l < 2; ++l) {
        zero_acc<<<(N * H + 255) / 256, 256, 0, stream>>>(xsum, magg, N);
        edge_mfma<<<tBlocks, 256, 0, stream>>>(
            erow, ecol, positions, xi, hi,
            W1B + (size_t)l * 3072, W2B + (size_t)l * 1024, CW1B + (size_t)l * 1024,
            edge_b2 + l * H, coord_b1 + l * H, coord_W2 + l * H,
            xsum, magg, E);
        node_kernel<<<nB256, 256, 0, stream>>>(
            deg, xi, hi, xsum, magg,
            node_W1 + l * (H * 2 * H), node_b1 + l * H,
            nw2t + l * (H * H),        node_b2 + l * H,
            xo, ho, N);
        const float* tx = xi; xi = xo; xo = (float*)tx;
        const float* th = hi; hi = ho; ho = (float*)th;
    }

    out_kernel<<<nB256, 256, 0, stream>>>(xi, lin_W, (float*)d_out, N);
}

// Round 11
// 714.011 us; speedup vs baseline: 2.4143x; 1.2042x over previous
//
#include <hip/hip_runtime.h>

#define H 32
#define DOUT 16
#define APITCH 104   // ushorts per A row (208 B)
#define NPITCH 72    // ushorts per node A row (144 B)

typedef unsigned short ushort_t;
typedef __attribute__((ext_vector_type(8))) short bf16x8;
typedef __attribute__((ext_vector_type(4))) float f32x4;

__device__ __forceinline__ float silu(float v) {
    return v * __builtin_amdgcn_rcpf(1.0f + __expf(-v));
}
__device__ __forceinline__ ushort_t f2bf(float f) {
    unsigned int u = __float_as_uint(f);
    unsigned int r = (u + 0x7FFFu + ((u >> 16) & 1u)) >> 16;  // RNE
    return (ushort_t)r;
}

// ---- CSR build -------------------------------------------------------------
__global__ __launch_bounds__(256) void zero_deg(int* __restrict__ deg, int N) {
    int i = blockIdx.x * blockDim.x + threadIdx.x;
    if (i < N) deg[i] = 0;
}

__global__ __launch_bounds__(256) void hist_kernel(const int* __restrict__ row,
                                                   int* __restrict__ deg, int E) {
    int e = blockIdx.x * blockDim.x + threadIdx.x;
    if (e < E) atomicAdd(&deg[row[e]], 1);
}

__global__ __launch_bounds__(1024) void scan_kernel(const int* __restrict__ deg,
                                                    int* __restrict__ start,
                                                    int* __restrict__ cursor, int N) {
    __shared__ int part[1024];
    int t = threadIdx.x;
    int ch = (N + 1023) >> 10;
    int lo = t * ch, hi = min(lo + ch, N);
    int s = 0;
    for (int i = lo; i < hi; ++i) s += deg[i];
    part[t] = s;
    __syncthreads();
    for (int off = 1; off < 1024; off <<= 1) {
        int v = (t >= off) ? part[t - off] : 0;
        __syncthreads();
        part[t] += v;
        __syncthreads();
    }
    int run = part[t] - s;
    for (int i = lo; i < hi; ++i) {
        start[i] = run; cursor[i] = run;
        run += deg[i];
    }
}

__global__ __launch_bounds__(256) void scatter_kernel(const int* __restrict__ row,
                                                      const int* __restrict__ col,
                                                      int* __restrict__ cursor,
                                                      int* __restrict__ ecol,
                                                      int* __restrict__ erow, int E) {
    int e = blockIdx.x * blockDim.x + threadIdx.x;
    if (e < E) {
        int r = row[e];
        int p = atomicAdd(&cursor[r], 1);
        ecol[p] = col[e];
        erow[p] = r;
    }
}

// ---- pack weights into MFMA B-fragment order (bf16) ------------------------
__global__ __launch_bounds__(256) void pack_weights(
    const float* __restrict__ eW1, const float* __restrict__ eb1,
    const float* __restrict__ eW2, const float* __restrict__ cW1,
    const float* __restrict__ nW1, const float* __restrict__ nW2,
    ushort_t* __restrict__ W1B, ushort_t* __restrict__ W2B,
    ushort_t* __restrict__ CW1B, ushort_t* __restrict__ NW1B,
    ushort_t* __restrict__ NW2B)
{
    int t = blockIdx.x * 256 + threadIdx.x;
    if (t < 6144) {  // edge W1: 2l * 3kc * 2nt * 64lane * 8j, K=96 padded, bias at k=68
        int j = t & 7; int r1 = t >> 3;
        int lane = r1 & 63; int r2 = r1 >> 6;
        int nt = r2 & 1; int r3 = r2 >> 1;
        int kc = r3 % 3; int l = r3 / 3;
        int n = 16 * nt + (lane & 15);
        int k = 32 * kc + 8 * (lane >> 4) + j;
        float v = 0.0f;
        if (k < 68) v = eW1[(l * 32 + n) * 68 + k];
        else if (k == 68) v = eb1[l * 32 + n];
        W1B[t] = f2bf(v);
    }
    if (t < 4096) {  // node W1: 2l * 2kc * 2nt * 64 * 8, K=64
        int j = t & 7; int lane = (t >> 3) & 63;
        int nt = (t >> 9) & 1; int kc = (t >> 10) & 1; int l = (t >> 11) & 1;
        int n = 16 * nt + (lane & 15);
        int k = 32 * kc + 8 * (lane >> 4) + j;
        NW1B[t] = f2bf(nW1[(l * 32 + n) * 64 + k]);
    }
    if (t < 2048) {  // edge W2 / coord W1 / node W2: K=32
        int j = t & 7; int lane = (t >> 3) & 63;
        int nt = (t >> 9) & 1; int l = t >> 10;
        int n = 16 * nt + (lane & 15);
        int k = 8 * (lane >> 4) + j;
        W2B[t]  = f2bf(eW2[(l * 32 + n) * 32 + k]);
        CW1B[t] = f2bf(cW1[(l * 32 + n) * 32 + k]);
        NW2B[t] = f2bf(nW2[(l * 32 + n) * 32 + k]);
    }
}

// ---- init: x, h fp32 + h bf16 mirror ---------------------------------------
__global__ __launch_bounds__(256) void init_nodes(
    const float* __restrict__ node_attrs, const float* __restrict__ positions,
    const float* __restrict__ projW, const float* __restrict__ embW,
    const float* __restrict__ embB,
    float* __restrict__ x, float* __restrict__ h, ushort_t* __restrict__ hb, int N)
{
    int n = blockIdx.x * blockDim.x + threadIdx.x;
    if (n >= N) return;
    float p0 = positions[3*n+0], p1 = positions[3*n+1], p2 = positions[3*n+2];
    #pragma unroll
    for (int i = 0; i < DOUT; ++i)
        x[(size_t)n*DOUT+i] = projW[i*3+0]*p0 + projW[i*3+1]*p1 + projW[i*3+2]*p2;
    float a0 = node_attrs[3*n+0], a1 = node_attrs[3*n+1], a2 = node_attrs[3*n+2];
    #pragma unroll
    for (int j = 0; j < H; ++j) {
        float v = embB[j] + embW[j*3+0]*a0 + embW[j*3+1]*a1 + embW[j*3+2]*a2;
        h[(size_t)n*H+j] = v;
        hb[(size_t)n*H+j] = f2bf(v);
    }
}

__global__ __launch_bounds__(256) void zero_acc(float* __restrict__ xsum,
                                                float* __restrict__ magg, int N) {
    int i = blockIdx.x * blockDim.x + threadIdx.x;
    if (i < N * DOUT) xsum[i] = 0.0f;
    if (i < N * H) magg[i] = 0.0f;
}

// ---- MFMA edge kernel: 64 edges/block; per-wave LDS slab reuse -------------
__global__ __launch_bounds__(256) void edge_mfma(
    const int* __restrict__ erow_g, const int* __restrict__ ecol_g,
    const float* __restrict__ positions,
    const float* __restrict__ x_in, const ushort_t* __restrict__ hbf,
    const ushort_t* __restrict__ W1B, const ushort_t* __restrict__ W2B,
    const ushort_t* __restrict__ CW1B,
    const float* __restrict__ eb2, const float* __restrict__ cb1,
    const float* __restrict__ cw2,
    float* __restrict__ xsum, float* __restrict__ magg, int E)
{
    __shared__ __align__(16) ushort_t Ain[64 * APITCH];  // wave slab reused for m1(bf16)+m2(fp32)
    __shared__ __align__(16) float    CDs[64 * 20];
    __shared__ float RP[256];
    __shared__ float CMs[64];
    __shared__ int ERO[64];
    __shared__ int RSTART[65];
    __shared__ int RNODE[64];
    __shared__ int NRUN;

    const int tid = threadIdx.x;
    const int t0 = blockIdx.x * 64;
    const int ntile = min(64, E - t0);
    const int lane = tid & 63;
    const int w = tid >> 6;
    const int nidx = lane & 15;
    const int q = lane >> 4;

    bf16x8 w1f[3][2], w2f[2], cwf[2];
    #pragma unroll
    for (int kc = 0; kc < 3; ++kc)
        #pragma unroll
        for (int nt = 0; nt < 2; ++nt)
            w1f[kc][nt] = *(const bf16x8*)(W1B + ((size_t)((kc*2+nt)*64 + lane)) * 8);
    #pragma unroll
    for (int nt = 0; nt < 2; ++nt) {
        w2f[nt] = *(const bf16x8*)(W2B + (size_t)(nt*64 + lane) * 8);
        cwf[nt] = *(const bf16x8*)(CW1B + (size_t)(nt*64 + lane) * 8);
    }
    float eb2v0 = eb2[nidx], eb2v1 = eb2[16 + nidx];
    float cb1v0 = cb1[nidx], cb1v1 = cb1[16 + nidx];
    float cw2v0 = cw2[nidx], cw2v1 = cw2[16 + nidx];

    // ---- Phase A0 (all 256 threads): zero K-tail, copy h bf16, cd partials -
    {
        int rr = tid >> 2, seg = tid & 3;
        *(uint4*)((char*)Ain + rr * 208 + 128 + seg * 16) = make_uint4(0,0,0,0);
    }
    {
        int e = tid >> 2, part = tid & 3;
        int s = t0 + e;
        uint4 v0 = make_uint4(0,0,0,0), v1 = v0;
        if (s < E) {
            int node = (part < 2) ? erow_g[s] : ecol_g[s];
            const uint4* hp = (const uint4*)(hbf + (size_t)node * H + (part & 1) * 16);
            v0 = hp[0]; v1 = hp[1];
        }
        uint4* dst = (uint4*)((char*)Ain + e * 208 + part * 32);
        dst[0] = v0; dst[1] = v1;
    }
    {
        int e = tid >> 2, qq = tid & 3;
        int s = t0 + e;
        float part = 0.0f;
        if (s < E) {
            int r = erow_g[s], c = ecol_g[s];
            float4 a = *(const float4*)(x_in + (size_t)r * DOUT + 4 * qq);
            float4 b = *(const float4*)(x_in + (size_t)c * DOUT + 4 * qq);
            float4 d;
            d.x = a.x - b.x; d.y = a.y - b.y; d.z = a.z - b.z; d.w = a.w - b.w;
            *(float4*)(CDs + e * 20 + 4 * qq) = d;
            part = d.x*d.x + d.y*d.y + d.z*d.z + d.w*d.w;
        }
        RP[tid] = part;
    }
    __syncthreads();

    // ---- Phase A1 (wave 0): radial, edge_attr, bias-one, ERO ---------------
    if (tid < 64) {
        int s = t0 + tid;
        if (s < E) {
            int r = erow_g[s], c = ecol_g[s];
            ERO[tid] = r;
            float radial = RP[4*tid] + RP[4*tid+1] + RP[4*tid+2] + RP[4*tid+3];
            ushort_t* rowp = Ain + tid * APITCH;
            rowp[64] = f2bf(radial);
            rowp[65] = f2bf(positions[3*r+0] - positions[3*c+0]);
            rowp[66] = f2bf(positions[3*r+1] - positions[3*c+1]);
            rowp[67] = f2bf(positions[3*r+2] - positions[3*c+2]);
            rowp[68] = 0x3F80;  // bf16(1.0) pairs with baked eb1
        } else {
            ERO[tid] = -1;
        }
    }
    __syncthreads();

    // ---- Phase B: MLP1 (68->32), K=96, 6 MFMAs -----------------------------
    const int mrow = 16 * w + nidx;
    bf16x8 af0 = *(const bf16x8*)(Ain + mrow * APITCH + 0  + 8 * q);
    bf16x8 af1 = *(const bf16x8*)(Ain + mrow * APITCH + 32 + 8 * q);
    bf16x8 af2 = *(const bf16x8*)(Ain + mrow * APITCH + 64 + 8 * q);
    f32x4 z4 = {0.0f, 0.0f, 0.0f, 0.0f};
    f32x4 acc0 = z4, acc1 = z4;
    acc0 = __builtin_amdgcn_mfma_f32_16x16x32_bf16(af0, w1f[0][0], acc0, 0, 0, 0);
    acc0 = __builtin_amdgcn_mfma_f32_16x16x32_bf16(af1, w1f[1][0], acc0, 0, 0, 0);
    acc0 = __builtin_amdgcn_mfma_f32_16x16x32_bf16(af2, w1f[2][0], acc0, 0, 0, 0);
    acc1 = __builtin_amdgcn_mfma_f32_16x16x32_bf16(af0, w1f[0][1], acc1, 0, 0, 0);
    acc1 = __builtin_amdgcn_mfma_f32_16x16x32_bf16(af1, w1f[1][1], acc1, 0, 0, 0);
    acc1 = __builtin_amdgcn_mfma_f32_16x16x32_bf16(af2, w1f[2][1], acc1, 0, 0, 0);

    // m1 -> own slab (bf16, pitch 40); A rows already consumed into af0..af2
    ushort_t* m1w = Ain + w * 16 * APITCH;
    #pragma unroll
    for (int r = 0; r < 4; ++r) {
        m1w[(4*q + r) * 40 + nidx]      = f2bf(silu(acc0[r]));
        m1w[(4*q + r) * 40 + 16 + nidx] = f2bf(silu(acc1[r]));
    }

    // ---- Phase C: MLP2 (32->32); m2 stored fp32 (pitch 36) -----------------
    bf16x8 a2 = *(const bf16x8*)(m1w + nidx * 40 + 8 * q);
    f32x4 b0 = __builtin_amdgcn_mfma_f32_16x16x32_bf16(a2, w2f[0], z4, 0, 0, 0);
    f32x4 b1 = __builtin_amdgcn_mfma_f32_16x16x32_bf16(a2, w2f[1], z4, 0, 0, 0);
    float* m2w = (float*)m1w;
    #pragma unroll
    for (int r = 0; r < 4; ++r) {
        m2w[(4*q + r) * 36 + nidx]      = silu(b0[r] + eb2v0);
        m2w[(4*q + r) * 36 + 16 + nidx] = silu(b1[r] + eb2v1);
    }

    // ---- Phase D: coord MLP ------------------------------------------------
    float4 f0 = *(const float4*)(m2w + nidx * 36 + 8 * q);
    float4 f1 = *(const float4*)(m2w + nidx * 36 + 8 * q + 4);
    bf16x8 a3;
    a3[0] = (short)f2bf(f0.x); a3[1] = (short)f2bf(f0.y);
    a3[2] = (short)f2bf(f0.z); a3[3] = (short)f2bf(f0.w);
    a3[4] = (short)f2bf(f1.x); a3[5] = (short)f2bf(f1.y);
    a3[6] = (short)f2bf(f1.z); a3[7] = (short)f2bf(f1.w);
    f32x4 c0 = __builtin_amdgcn_mfma_f32_16x16x32_bf16(a3, cwf[0], z4, 0, 0, 0);
    f32x4 c1 = __builtin_amdgcn_mfma_f32_16x16x32_bf16(a3, cwf[1], z4, 0, 0, 0);
    float p[4];
    #pragma unroll
    for (int r = 0; r < 4; ++r)
        p[r] = silu(c0[r] + cb1v0) * cw2v0 + silu(c1[r] + cb1v1) * cw2v1;
    #pragma unroll
    for (int m = 1; m < 16; m <<= 1) {
        #pragma unroll
        for (int r = 0; r < 4; ++r) p[r] += __shfl_xor(p[r], m, 64);
    }
    if (nidx == 0) {
        #pragma unroll
        for (int r = 0; r < 4; ++r) CMs[16*w + 4*q + r] = p[r];
    }
    __syncthreads();

    // ---- Phase E: ballot run detection + segmented sums + few atomics ------
    if (tid < 64) {
        bool f = (tid < ntile) && (tid == 0 || ERO[tid] != ERO[tid - 1]);
        unsigned long long mask = __ballot(f);
        if (f) {
            int rank = (int)__popcll(mask & ((1ull << tid) - 1ull));
            RSTART[rank] = tid;
            RNODE[rank] = ERO[tid];
        }
        if (tid == 0) {
            int nr = (int)__popcll(mask);
            NRUN = nr;
            RSTART[nr] = ntile;
        }
    }
    __syncthreads();
    int nrun = NRUN;
    for (int idx = tid; idx < nrun * 48; idx += 256) {
        int k = idx / 48, d = idx - k * 48;
        int s = RSTART[k], en = RSTART[k + 1];
        int node = RNODE[k];
        float sum = 0.0f;
        if (d < 32) {
            for (int e = s; e < en; ++e)
                sum += *((const float*)((const char*)Ain + (e >> 4) * 3328) + (e & 15) * 36 + d);
            unsafeAtomicAdd(&magg[(size_t)node * H + d], sum);
        } else {
            int dd = d - 32;
            for (int e = s; e < en; ++e)
                sum += CDs[e * 20 + dd] * CMs[e];
            unsafeAtomicAdd(&xsum[(size_t)node * DOUT + dd], sum);
        }
    }
}

// ---- MFMA node kernel: 64 nodes/block, no gather/scatter -------------------
__global__ __launch_bounds__(256) void node_mfma(
    const int* __restrict__ deg,
    const float* __restrict__ x_in, const float* __restrict__ h_in,
    const ushort_t* __restrict__ hbf_in,
    const float* __restrict__ xsum, const float* __restrict__ magg,
    const ushort_t* __restrict__ W1B, const ushort_t* __restrict__ W2B,
    const float* __restrict__ b1g, const float* __restrict__ b2g,
    float* __restrict__ x_out, float* __restrict__ h_out,
    ushort_t* __restrict__ hbf_out, int N)
{
    __shared__ __align__(16) ushort_t Nin[64 * NPITCH];

    const int tid = threadIdx.x;
    const int n0 = blockIdx.x * 64;
    const int lane = tid & 63;
    const int w = tid >> 6;
    const int nidx = lane & 15;
    const int q = lane >> 4;

    bf16x8 w1f[2][2], w2f[2];
    #pragma unroll
    for (int kc = 0; kc < 2; ++kc)
        #pragma unroll
        for (int nt = 0; nt < 2; ++nt)
            w1f[kc][nt] = *(const bf16x8*)(W1B + (size_t)((kc*2+nt)*64 + lane) * 8);
    #pragma unroll
    for (int nt = 0; nt < 2; ++nt)
        w2f[nt] = *(const bf16x8*)(W2B + (size_t)(nt*64 + lane) * 8);
    float b1v0 = b1g[nidx], b1v1 = b1g[16+nidx];
    float b2v0 = b2g[nidx], b2v1 = b2g[16+nidx];

    // stage nin = [h bf16 | magg->bf16]
    {
        int e = tid >> 2, part = tid & 3;
        int n = n0 + e;
        uint4 v0 = make_uint4(0,0,0,0), v1 = v0;
        if (n < N) {
            if (part < 2) {
                const uint4* hp = (const uint4*)(hbf_in + (size_t)n * H + part * 16);
                v0 = hp[0]; v1 = hp[1];
            } else {
                const float4* mp = (const float4*)(magg + (size_t)n * H + (part & 1) * 16);
                float4 f[4] = {mp[0], mp[1], mp[2], mp[3]};
                unsigned u[8];
                #pragma unroll
                for (int qq = 0; qq < 4; ++qq) {
                    u[2*qq]   = (unsigned)f2bf(f[qq].x) | ((unsigned)f2bf(f[qq].y) << 16);
                    u[2*qq+1] = (unsigned)f2bf(f[qq].z) | ((unsigned)f2bf(f[qq].w) << 16);
                }
                v0 = make_uint4(u[0], u[1], u[2], u[3]);
                v1 = make_uint4(u[4], u[5], u[6], u[7]);
            }
        }
        uint4* dst = (uint4*)((char*)Nin + e * 144 + part * 32);
        dst[0] = v0; dst[1] = v1;
    }

    // x update (independent of LDS)
    for (int idx = tid; idx < 64 * DOUT; idx += 256) {
        int n = n0 + (idx >> 4);
        if (n < N) {
            int d = idx & 15;
            size_t off = (size_t)n * DOUT + d;
            float inv = __builtin_amdgcn_rcpf(fmaxf((float)deg[n], 1.0f));
            x_out[off] = x_in[off] + xsum[off] * inv;
        }
    }
    __syncthreads();

    const int mrow = 16 * w + nidx;
    bf16x8 a0 = *(const bf16x8*)(Nin + mrow * NPITCH + 8 * q);
    bf16x8 a1 = *(const bf16x8*)(Nin + mrow * NPITCH + 32 + 8 * q);
    f32x4 z4 = {0.0f, 0.0f, 0.0f, 0.0f};
    f32x4 acc0 = z4, acc1 = z4;
    acc0 = __builtin_amdgcn_mfma_f32_16x16x32_bf16(a0, w1f[0][0], acc0, 0, 0, 0);
    acc0 = __builtin_amdgcn_mfma_f32_16x16x32_bf16(a1, w1f[1][0], acc0, 0, 0, 0);
    acc1 = __builtin_amdgcn_mfma_f32_16x16x32_bf16(a0, w1f[0][1], acc1, 0, 0, 0);
    acc1 = __builtin_amdgcn_mfma_f32_16x16x32_bf16(a1, w1f[1][1], acc1, 0, 0, 0);

    ushort_t* u1w = Nin + w * 16 * NPITCH;   // own slab reuse (2304 B >= 1280 B)
    #pragma unroll
    for (int r = 0; r < 4; ++r) {
        u1w[(4*q + r) * 40 + nidx]      = f2bf(silu(acc0[r] + b1v0));
        u1w[(4*q + r) * 40 + 16 + nidx] = f2bf(silu(acc1[r] + b1v1));
    }
    bf16x8 au = *(const bf16x8*)(u1w + nidx * 40 + 8 * q);
    f32x4 d0 = __builtin_amdgcn_mfma_f32_16x16x32_bf16(au, w2f[0], z4, 0, 0, 0);
    f32x4 d1 = __builtin_amdgcn_mfma_f32_16x16x32_bf16(au, w2f[1], z4, 0, 0, 0);
    #pragma unroll
    for (int r = 0; r < 4; ++r) {
        int n = n0 + 16*w + 4*q + r;
        if (n < N) {
            size_t o0 = (size_t)n * H + nidx, o1 = o0 + 16;
            float h0 = h_in[o0] + d0[r] + b2v0;
            float h1 = h_in[o1] + d1[r] + b2v1;
            h_out[o0] = h0; h_out[o1] = h1;
            hbf_out[o0] = f2bf(h0); hbf_out[o1] = f2bf(h1);
        }
    }
}

// ---- output ----------------------------------------------------------------
__global__ __launch_bounds__(256) void out_kernel(
    const float* __restrict__ x, const float* __restrict__ lin,
    float* __restrict__ out, int N)
{
    int n = blockIdx.x * blockDim.x + threadIdx.x;
    if (n >= N) return;
    float xr[DOUT];
    const float4* xp = (const float4*)(x + (size_t)n * DOUT);
    #pragma unroll
    for (int qq = 0; qq < DOUT/4; ++qq) {
        float4 v = xp[qq];
        xr[4*qq+0]=v.x; xr[4*qq+1]=v.y; xr[4*qq+2]=v.z; xr[4*qq+3]=v.w;
    }
    #pragma unroll
    for (int i = 0; i < 3; ++i) {
        float a = 0.0f;
        #pragma unroll
        for (int k = 0; k < DOUT; ++k) a += xr[k] * lin[i*DOUT+k];
        out[(size_t)n*3+i] = a;
    }
}

extern "C" void kernel_launch(void* const* d_in, const int* in_sizes, int n_in,
                              void* d_out, int out_size, void* d_ws, size_t ws_size,
                              hipStream_t stream) {
    const float* node_attrs = (const float*)d_in[0];
    const float* positions  = (const float*)d_in[1];
    const int*   edge_index = (const int*)d_in[2];
    const float* proj_W   = (const float*)d_in[3];
    const float* emb_in_W = (const float*)d_in[4];
    const float* emb_in_b = (const float*)d_in[5];
    const float* edge_W1  = (const float*)d_in[6];
    const float* edge_b1  = (const float*)d_in[7];
    const float* edge_W2  = (const float*)d_in[8];
    const float* edge_b2  = (const float*)d_in[9];
    const float* node_W1  = (const float*)d_in[10];
    const float* node_b1  = (const float*)d_in[11];
    const float* node_W2  = (const float*)d_in[12];
    const float* node_b2  = (const float*)d_in[13];
    const float* coord_W1 = (const float*)d_in[14];
    const float* coord_b1 = (const float*)d_in[15];
    const float* coord_W2 = (const float*)d_in[16];
    const float* lin_W    = (const float*)d_in[19];

    const int N = in_sizes[0] / 3;
    const int E = in_sizes[2] / 2;
    const int* row = edge_index;
    const int* col = edge_index + E;

    float* x0 = (float*)d_ws;
    float* h0 = x0 + (size_t)DOUT * N;
    float* x1 = h0 + (size_t)H * N;
    float* h1 = x1 + (size_t)DOUT * N;
    float* xsum = h1 + (size_t)H * N;
    float* magg = xsum + (size_t)DOUT * N;
    ushort_t* hb   = (ushort_t*)(magg + (size_t)H * N);  // 32N ushorts (single buffer)
    ushort_t* W1B  = hb + (size_t)H * N;                 // 6144
    ushort_t* W2B  = W1B + 6144;                         // 2048
    ushort_t* CW1B = W2B + 2048;                         // 2048
    ushort_t* NW1B = CW1B + 2048;                        // 4096
    ushort_t* NW2B = NW1B + 4096;                        // 2048
    int* deg    = (int*)(NW2B + 2048);
    int* startv = deg + N;
    int* cursor = startv + N;
    int* ecol   = cursor + N;
    int* erow   = ecol + E;

    int nB256 = (N + 255) / 256;
    int eB256 = (E + 255) / 256;
    int tBlocks = (E + 63) / 64;
    int nTiles = (N + 63) / 64;

    zero_deg<<<nB256, 256, 0, stream>>>(deg, N);
    hist_kernel<<<eB256, 256, 0, stream>>>(row, deg, E);
    scan_kernel<<<1, 1024, 0, stream>>>(deg, startv, cursor, N);
    scatter_kernel<<<eB256, 256, 0, stream>>>(row, col, cursor, ecol, erow, E);
    pack_weights<<<24, 256, 0, stream>>>(edge_W1, edge_b1, edge_W2, coord_W1,
                                         node_W1, node_W2,
                                         W1B, W2B, CW1B, NW1B, NW2B);

    init_nodes<<<nB256, 256, 0, stream>>>(node_attrs, positions,
                                          proj_W, emb_in_W, emb_in_b, x0, h0, hb, N);

    const float* xi = x0; const float* hi = h0;
    float* xo = x1; float* ho = h1;
    for (int l = 0; l < 2; ++l) {
        zero_acc<<<(N * H + 255) / 256, 256, 0, stream>>>(xsum, magg, N);
        edge_mfma<<<tBlocks, 256, 0, stream>>>(
            erow, ecol, positions, xi, hb,
            W1B + (size_t)l * 3072, W2B + (size_t)l * 1024, CW1B + (size_t)l * 1024,
            edge_b2 + l * H, coord_b1 + l * H, coord_W2 + l * H,
            xsum, magg, E);
        node_mfma<<<nTiles, 256, 0, stream>>>(
            deg, xi, hi, hb, xsum, magg,
            NW1B + (size_t)l * 2048, NW2B + (size_t)l * 1024,
            node_b1 + l * H, node_b2 + l * H,
            xo, ho, hb, N);
        const float* tx = xi; xi = xo; xo = (float*)tx;
        const float* th = hi; hi = ho; ho = (float*)th;
    }

    out_kernel<<<nB256, 256, 0, stream>>>(xi, lin_W, (float*)d_out, N);
}

// Round 12
// 713.309 us; speedup vs baseline: 2.4167x; 1.0010x over previous
//
#include <hip/hip_runtime.h>

#define H 32
#define DOUT 16
#define APITCH 104   // ushorts per A row (208 B)
#define NPITCH 72    // ushorts per node A row (144 B)

typedef unsigned short ushort_t;
typedef __attribute__((ext_vector_type(8))) short bf16x8;
typedef __attribute__((ext_vector_type(4))) float f32x4;

__device__ __forceinline__ float silu(float v) {
    return v * __builtin_amdgcn_rcpf(1.0f + __expf(-v));
}
__device__ __forceinline__ ushort_t f2bf(float f) {
    unsigned int u = __float_as_uint(f);
    unsigned int r = (u + 0x7FFFu + ((u >> 16) & 1u)) >> 16;  // RNE
    return (ushort_t)r;
}

// ---- CSR build -------------------------------------------------------------
__global__ __launch_bounds__(256) void hist_kernel(const int* __restrict__ row,
                                                   int* __restrict__ deg, int E) {
    int e = blockIdx.x * blockDim.x + threadIdx.x;
    if (e < E) atomicAdd(&deg[row[e]], 1);
}

__global__ __launch_bounds__(1024) void scan_kernel(const int* __restrict__ deg,
                                                    int* __restrict__ start,
                                                    int* __restrict__ cursor, int N) {
    __shared__ int part[1024];
    int t = threadIdx.x;
    int ch = (N + 1023) >> 10;
    int lo = t * ch, hi = min(lo + ch, N);
    int s = 0;
    for (int i = lo; i < hi; ++i) s += deg[i];
    part[t] = s;
    __syncthreads();
    for (int off = 1; off < 1024; off <<= 1) {
        int v = (t >= off) ? part[t - off] : 0;
        __syncthreads();
        part[t] += v;
        __syncthreads();
    }
    int run = part[t] - s;
    for (int i = lo; i < hi; ++i) {
        start[i] = run; cursor[i] = run;
        run += deg[i];
    }
}

// one scattered int2 store per edge: ee[p] = {col, row}
__global__ __launch_bounds__(256) void scatter_kernel(const int* __restrict__ row,
                                                      const int* __restrict__ col,
                                                      int* __restrict__ cursor,
                                                      int2* __restrict__ ee, int E) {
    int e = blockIdx.x * blockDim.x + threadIdx.x;
    if (e < E) {
        int r = row[e];
        int p = atomicAdd(&cursor[r], 1);
        ee[p] = make_int2(col[e], r);
    }
}

// ---- fused init (x, h fp32 + bf16 mirror) + weight pack --------------------
__global__ __launch_bounds__(256) void init_pack(
    const float* __restrict__ node_attrs, const float* __restrict__ positions,
    const float* __restrict__ projW, const float* __restrict__ embW,
    const float* __restrict__ embB,
    const float* __restrict__ eW1, const float* __restrict__ eb1,
    const float* __restrict__ eW2, const float* __restrict__ cW1,
    const float* __restrict__ nW1, const float* __restrict__ nW2,
    float* __restrict__ x, float* __restrict__ h, ushort_t* __restrict__ hb,
    ushort_t* __restrict__ W1B, ushort_t* __restrict__ W2B,
    ushort_t* __restrict__ CW1B, ushort_t* __restrict__ NW1B,
    ushort_t* __restrict__ NW2B, int N)
{
    int g = blockIdx.x * blockDim.x + threadIdx.x;
    if (g < N) {
        int n = g;
        float p0 = positions[3*n+0], p1 = positions[3*n+1], p2 = positions[3*n+2];
        #pragma unroll
        for (int i = 0; i < DOUT; ++i)
            x[(size_t)n*DOUT+i] = projW[i*3+0]*p0 + projW[i*3+1]*p1 + projW[i*3+2]*p2;
        float a0 = node_attrs[3*n+0], a1 = node_attrs[3*n+1], a2 = node_attrs[3*n+2];
        #pragma unroll
        for (int j = 0; j < H; ++j) {
            float v = embB[j] + embW[j*3+0]*a0 + embW[j*3+1]*a1 + embW[j*3+2]*a2;
            h[(size_t)n*H+j] = v;
            hb[(size_t)n*H+j] = f2bf(v);
        }
        return;
    }
    int t = g - N;
    if (t < 6144) {  // edge W1: K=96 padded, bias baked at k=68
        int j = t & 7; int r1 = t >> 3;
        int lane = r1 & 63; int r2 = r1 >> 6;
        int nt = r2 & 1; int r3 = r2 >> 1;
        int kc = r3 % 3; int l = r3 / 3;
        int n = 16 * nt + (lane & 15);
        int k = 32 * kc + 8 * (lane >> 4) + j;
        float v = 0.0f;
        if (k < 68) v = eW1[(l * 32 + n) * 68 + k];
        else if (k == 68) v = eb1[l * 32 + n];
        W1B[t] = f2bf(v);
    }
    if (t < 4096) {  // node W1: K=64
        int j = t & 7; int lane = (t >> 3) & 63;
        int nt = (t >> 9) & 1; int kc = (t >> 10) & 1; int l = (t >> 11) & 1;
        int n = 16 * nt + (lane & 15);
        int k = 32 * kc + 8 * (lane >> 4) + j;
        NW1B[t] = f2bf(nW1[(l * 32 + n) * 64 + k]);
    }
    if (t < 2048) {  // edge W2 / coord W1 / node W2: K=32
        int j = t & 7; int lane = (t >> 3) & 63;
        int nt = (t >> 9) & 1; int l = t >> 10;
        int n = 16 * nt + (lane & 15);
        int k = 8 * (lane >> 4) + j;
        W2B[t]  = f2bf(eW2[(l * 32 + n) * 32 + k]);
        CW1B[t] = f2bf(cW1[(l * 32 + n) * 32 + k]);
        NW2B[t] = f2bf(nW2[(l * 32 + n) * 32 + k]);
    }
}

// ---- MFMA edge kernel: 64 edges/block --------------------------------------
__global__ __launch_bounds__(256) void edge_mfma(
    const int2* __restrict__ ee,
    const float* __restrict__ positions,
    const float* __restrict__ x_in, const ushort_t* __restrict__ hbf,
    const ushort_t* __restrict__ W1B, const ushort_t* __restrict__ W2B,
    const ushort_t* __restrict__ CW1B,
    const float* __restrict__ eb2, const float* __restrict__ cb1,
    const float* __restrict__ cw2,
    float* __restrict__ xsum, float* __restrict__ magg, int E)
{
    __shared__ __align__(16) ushort_t Ain[64 * APITCH];  // wave slab reused for m1/m2
    __shared__ __align__(16) float    CDs[64 * 20];
    __shared__ float RP[256];
    __shared__ float CMs[64];
    __shared__ int ERO[64];
    __shared__ int RSTART[65];
    __shared__ int RNODE[64];
    __shared__ int NRUN;

    const int tid = threadIdx.x;
    const int t0 = blockIdx.x * 64;
    const int ntile = min(64, E - t0);
    const int lane = tid & 63;
    const int w = tid >> 6;
    const int nidx = lane & 15;
    const int q = lane >> 4;

    bf16x8 w1f[3][2], w2f[2], cwf[2];
    #pragma unroll
    for (int kc = 0; kc < 3; ++kc)
        #pragma unroll
        for (int nt = 0; nt < 2; ++nt)
            w1f[kc][nt] = *(const bf16x8*)(W1B + ((size_t)((kc*2+nt)*64 + lane)) * 8);
    #pragma unroll
    for (int nt = 0; nt < 2; ++nt) {
        w2f[nt] = *(const bf16x8*)(W2B + (size_t)(nt*64 + lane) * 8);
        cwf[nt] = *(const bf16x8*)(CW1B + (size_t)(nt*64 + lane) * 8);
    }
    float eb2v0 = eb2[nidx], eb2v1 = eb2[16 + nidx];
    float cb1v0 = cb1[nidx], cb1v1 = cb1[16 + nidx];
    float cw2v0 = cw2[nidx], cw2v1 = cw2[16 + nidx];

    // ---- Phase A0: zero K-tail, copy h bf16, cd partials -------------------
    {
        int rr = tid >> 2, seg = tid & 3;
        *(uint4*)((char*)Ain + rr * 208 + 128 + seg * 16) = make_uint4(0,0,0,0);
    }
    {
        int e = tid >> 2, part = tid & 3;
        int s = t0 + e;
        uint4 v0 = make_uint4(0,0,0,0), v1 = v0;
        if (s < E) {
            int2 p = ee[s];
            int node = (part < 2) ? p.y : p.x;
            const uint4* hp = (const uint4*)(hbf + (size_t)node * H + (part & 1) * 16);
            v0 = hp[0]; v1 = hp[1];
        }
        uint4* dst = (uint4*)((char*)Ain + e * 208 + part * 32);
        dst[0] = v0; dst[1] = v1;
    }
    {
        int e = tid >> 2, qq = tid & 3;
        int s = t0 + e;
        float part = 0.0f;
        if (s < E) {
            int2 p = ee[s];
            float4 a = *(const float4*)(x_in + (size_t)p.y * DOUT + 4 * qq);
            float4 b = *(const float4*)(x_in + (size_t)p.x * DOUT + 4 * qq);
            float4 d;
            d.x = a.x - b.x; d.y = a.y - b.y; d.z = a.z - b.z; d.w = a.w - b.w;
            *(float4*)(CDs + e * 20 + 4 * qq) = d;
            part = d.x*d.x + d.y*d.y + d.z*d.z + d.w*d.w;
        }
        RP[tid] = part;
    }
    __syncthreads();

    // ---- Phase A1 (wave 0): radial, edge_attr, bias-one, ERO ---------------
    if (tid < 64) {
        int s = t0 + tid;
        if (s < E) {
            int2 p = ee[s];
            ERO[tid] = p.y;
            float radial = RP[4*tid] + RP[4*tid+1] + RP[4*tid+2] + RP[4*tid+3];
            ushort_t* rowp = Ain + tid * APITCH;
            rowp[64] = f2bf(radial);
            rowp[65] = f2bf(positions[3*p.y+0] - positions[3*p.x+0]);
            rowp[66] = f2bf(positions[3*p.y+1] - positions[3*p.x+1]);
            rowp[67] = f2bf(positions[3*p.y+2] - positions[3*p.x+2]);
            rowp[68] = 0x3F80;  // bf16(1.0) pairs with baked eb1
        } else {
            ERO[tid] = -1;
        }
    }
    __syncthreads();

    // ---- Phase B: MLP1 (68->32), K=96, 6 MFMAs -----------------------------
    const int mrow = 16 * w + nidx;
    bf16x8 af0 = *(const bf16x8*)(Ain + mrow * APITCH + 0  + 8 * q);
    bf16x8 af1 = *(const bf16x8*)(Ain + mrow * APITCH + 32 + 8 * q);
    bf16x8 af2 = *(const bf16x8*)(Ain + mrow * APITCH + 64 + 8 * q);
    f32x4 z4 = {0.0f, 0.0f, 0.0f, 0.0f};
    f32x4 acc0 = z4, acc1 = z4;
    acc0 = __builtin_amdgcn_mfma_f32_16x16x32_bf16(af0, w1f[0][0], acc0, 0, 0, 0);
    acc0 = __builtin_amdgcn_mfma_f32_16x16x32_bf16(af1, w1f[1][0], acc0, 0, 0, 0);
    acc0 = __builtin_amdgcn_mfma_f32_16x16x32_bf16(af2, w1f[2][0], acc0, 0, 0, 0);
    acc1 = __builtin_amdgcn_mfma_f32_16x16x32_bf16(af0, w1f[0][1], acc1, 0, 0, 0);
    acc1 = __builtin_amdgcn_mfma_f32_16x16x32_bf16(af1, w1f[1][1], acc1, 0, 0, 0);
    acc1 = __builtin_amdgcn_mfma_f32_16x16x32_bf16(af2, w1f[2][1], acc1, 0, 0, 0);

    ushort_t* m1w = Ain + w * 16 * APITCH;   // own-slab reuse
    #pragma unroll
    for (int r = 0; r < 4; ++r) {
        m1w[(4*q + r) * 40 + nidx]      = f2bf(silu(acc0[r]));
        m1w[(4*q + r) * 40 + 16 + nidx] = f2bf(silu(acc1[r]));
    }

    // ---- Phase C: MLP2 (32->32); m2 stored fp32 (pitch 36) -----------------
    bf16x8 a2 = *(const bf16x8*)(m1w + nidx * 40 + 8 * q);
    f32x4 b0 = __builtin_amdgcn_mfma_f32_16x16x32_bf16(a2, w2f[0], z4, 0, 0, 0);
    f32x4 b1 = __builtin_amdgcn_mfma_f32_16x16x32_bf16(a2, w2f[1], z4, 0, 0, 0);
    float* m2w = (float*)m1w;
    #pragma unroll
    for (int r = 0; r < 4; ++r) {
        m2w[(4*q + r) * 36 + nidx]      = silu(b0[r] + eb2v0);
        m2w[(4*q + r) * 36 + 16 + nidx] = silu(b1[r] + eb2v1);
    }

    // ---- Phase D: coord MLP ------------------------------------------------
    float4 f0 = *(const float4*)(m2w + nidx * 36 + 8 * q);
    float4 f1 = *(const float4*)(m2w + nidx * 36 + 8 * q + 4);
    bf16x8 a3;
    a3[0] = (short)f2bf(f0.x); a3[1] = (short)f2bf(f0.y);
    a3[2] = (short)f2bf(f0.z); a3[3] = (short)f2bf(f0.w);
    a3[4] = (short)f2bf(f1.x); a3[5] = (short)f2bf(f1.y);
    a3[6] = (short)f2bf(f1.z); a3[7] = (short)f2bf(f1.w);
    f32x4 c0 = __builtin_amdgcn_mfma_f32_16x16x32_bf16(a3, cwf[0], z4, 0, 0, 0);
    f32x4 c1 = __builtin_amdgcn_mfma_f32_16x16x32_bf16(a3, cwf[1], z4, 0, 0, 0);
    float p[4];
    #pragma unroll
    for (int r = 0; r < 4; ++r)
        p[r] = silu(c0[r] + cb1v0) * cw2v0 + silu(c1[r] + cb1v1) * cw2v1;
    #pragma unroll
    for (int m = 1; m < 16; m <<= 1) {
        #pragma unroll
        for (int r = 0; r < 4; ++r) p[r] += __shfl_xor(p[r], m, 64);
    }
    if (nidx == 0) {
        #pragma unroll
        for (int r = 0; r < 4; ++r) CMs[16*w + 4*q + r] = p[r];
    }
    __syncthreads();

    // ---- Phase E: ballot run detection + segmented sums + few atomics ------
    if (tid < 64) {
        bool f = (tid < ntile) && (tid == 0 || ERO[tid] != ERO[tid - 1]);
        unsigned long long mask = __ballot(f);
        if (f) {
            int rank = (int)__popcll(mask & ((1ull << tid) - 1ull));
            RSTART[rank] = tid;
            RNODE[rank] = ERO[tid];
        }
        if (tid == 0) {
            int nr = (int)__popcll(mask);
            NRUN = nr;
            RSTART[nr] = ntile;
        }
    }
    __syncthreads();
    int nrun = NRUN;
    for (int idx = tid; idx < nrun * 48; idx += 256) {
        int k = idx / 48, d = idx - k * 48;
        int s = RSTART[k], en = RSTART[k + 1];
        int node = RNODE[k];
        float sum = 0.0f;
        if (d < 32) {
            for (int e = s; e < en; ++e)
                sum += *((const float*)((const char*)Ain + (e >> 4) * 3328) + (e & 15) * 36 + d);
            unsafeAtomicAdd(&magg[(size_t)node * H + d], sum);
        } else {
            int dd = d - 32;
            for (int e = s; e < en; ++e)
                sum += CDs[e * 20 + dd] * CMs[e];
            unsafeAtomicAdd(&xsum[(size_t)node * DOUT + dd], sum);
        }
    }
}

// ---- MFMA node kernel: 64 nodes/block; re-zeros magg/xsum after read -------
__global__ __launch_bounds__(256) void node_mfma(
    const int* __restrict__ deg,
    const float* __restrict__ x_in, const float* __restrict__ h_in,
    const ushort_t* __restrict__ hbf_in,
    float* __restrict__ xsum, float* __restrict__ magg,
    const ushort_t* __restrict__ W1B, const ushort_t* __restrict__ W2B,
    const float* __restrict__ b1g, const float* __restrict__ b2g,
    float* __restrict__ x_out, float* __restrict__ h_out,
    ushort_t* __restrict__ hbf_out, int N)
{
    __shared__ __align__(16) ushort_t Nin[64 * NPITCH];

    const int tid = threadIdx.x;
    const int n0 = blockIdx.x * 64;
    const int lane = tid & 63;
    const int w = tid >> 6;
    const int nidx = lane & 15;
    const int q = lane >> 4;

    bf16x8 w1f[2][2], w2f[2];
    #pragma unroll
    for (int kc = 0; kc < 2; ++kc)
        #pragma unroll
        for (int nt = 0; nt < 2; ++nt)
            w1f[kc][nt] = *(const bf16x8*)(W1B + (size_t)((kc*2+nt)*64 + lane) * 8);
    #pragma unroll
    for (int nt = 0; nt < 2; ++nt)
        w2f[nt] = *(const bf16x8*)(W2B + (size_t)(nt*64 + lane) * 8);
    float b1v0 = b1g[nidx], b1v1 = b1g[16+nidx];
    float b2v0 = b2g[nidx], b2v1 = b2g[16+nidx];

    // stage nin = [h bf16 | magg->bf16]; zero magg after read
    {
        int e = tid >> 2, part = tid & 3;
        int n = n0 + e;
        uint4 v0 = make_uint4(0,0,0,0), v1 = v0;
        if (n < N) {
            if (part < 2) {
                const uint4* hp = (const uint4*)(hbf_in + (size_t)n * H + part * 16);
                v0 = hp[0]; v1 = hp[1];
            } else {
                float4* mp = (float4*)(magg + (size_t)n * H + (part & 1) * 16);
                float4 f[4] = {mp[0], mp[1], mp[2], mp[3]};
                unsigned u[8];
                #pragma unroll
                for (int qq = 0; qq < 4; ++qq) {
                    u[2*qq]   = (unsigned)f2bf(f[qq].x) | ((unsigned)f2bf(f[qq].y) << 16);
                    u[2*qq+1] = (unsigned)f2bf(f[qq].z) | ((unsigned)f2bf(f[qq].w) << 16);
                }
                v0 = make_uint4(u[0], u[1], u[2], u[3]);
                v1 = make_uint4(u[4], u[5], u[6], u[7]);
                float4 z = {0.0f, 0.0f, 0.0f, 0.0f};
                mp[0] = z; mp[1] = z; mp[2] = z; mp[3] = z;
            }
        }
        uint4* dst = (uint4*)((char*)Nin + e * 144 + part * 32);
        dst[0] = v0; dst[1] = v1;
    }

    // x update; zero xsum after read
    for (int idx = tid; idx < 64 * DOUT; idx += 256) {
        int n = n0 + (idx >> 4);
        if (n < N) {
            int d = idx & 15;
            size_t off = (size_t)n * DOUT + d;
            float inv = __builtin_amdgcn_rcpf(fmaxf((float)deg[n], 1.0f));
            x_out[off] = x_in[off] + xsum[off] * inv;
            xsum[off] = 0.0f;
        }
    }
    __syncthreads();

    const int mrow = 16 * w + nidx;
    bf16x8 a0 = *(const bf16x8*)(Nin + mrow * NPITCH + 8 * q);
    bf16x8 a1 = *(const bf16x8*)(Nin + mrow * NPITCH + 32 + 8 * q);
    f32x4 z4 = {0.0f, 0.0f, 0.0f, 0.0f};
    f32x4 acc0 = z4, acc1 = z4;
    acc0 = __builtin_amdgcn_mfma_f32_16x16x32_bf16(a0, w1f[0][0], acc0, 0, 0, 0);
    acc0 = __builtin_amdgcn_mfma_f32_16x16x32_bf16(a1, w1f[1][0], acc0, 0, 0, 0);
    acc1 = __builtin_amdgcn_mfma_f32_16x16x32_bf16(a0, w1f[0][1], acc1, 0, 0, 0);
    acc1 = __builtin_amdgcn_mfma_f32_16x16x32_bf16(a1, w1f[1][1], acc1, 0, 0, 0);

    ushort_t* u1w = Nin + w * 16 * NPITCH;   // own slab reuse
    #pragma unroll
    for (int r = 0; r < 4; ++r) {
        u1w[(4*q + r) * 40 + nidx]      = f2bf(silu(acc0[r] + b1v0));
        u1w[(4*q + r) * 40 + 16 + nidx] = f2bf(silu(acc1[r] + b1v1));
    }
    bf16x8 au = *(const bf16x8*)(u1w + nidx * 40 + 8 * q);
    f32x4 d0 = __builtin_amdgcn_mfma_f32_16x16x32_bf16(au, w2f[0], z4, 0, 0, 0);
    f32x4 d1 = __builtin_amdgcn_mfma_f32_16x16x32_bf16(au, w2f[1], z4, 0, 0, 0);
    #pragma unroll
    for (int r = 0; r < 4; ++r) {
        int n = n0 + 16*w + 4*q + r;
        if (n < N) {
            size_t o0 = (size_t)n * H + nidx, o1 = o0 + 16;
            float h0 = h_in[o0] + d0[r] + b2v0;
            float h1 = h_in[o1] + d1[r] + b2v1;
            h_out[o0] = h0; h_out[o1] = h1;
            hbf_out[o0] = f2bf(h0); hbf_out[o1] = f2bf(h1);
        }
    }
}

// ---- output ----------------------------------------------------------------
__global__ __launch_bounds__(256) void out_kernel(
    const float* __restrict__ x, const float* __restrict__ lin,
    float* __restrict__ out, int N)
{
    int n = blockIdx.x * blockDim.x + threadIdx.x;
    if (n >= N) return;
    float xr[DOUT];
    const float4* xp = (const float4*)(x + (size_t)n * DOUT);
    #pragma unroll
    for (int qq = 0; qq < DOUT/4; ++qq) {
        float4 v = xp[qq];
        xr[4*qq+0]=v.x; xr[4*qq+1]=v.y; xr[4*qq+2]=v.z; xr[4*qq+3]=v.w;
    }
    #pragma unroll
    for (int i = 0; i < 3; ++i) {
        float a = 0.0f;
        #pragma unroll
        for (int k = 0; k < DOUT; ++k) a += xr[k] * lin[i*DOUT+k];
        out[(size_t)n*3+i] = a;
    }
}

extern "C" void kernel_launch(void* const* d_in, const int* in_sizes, int n_in,
                              void* d_out, int out_size, void* d_ws, size_t ws_size,
                              hipStream_t stream) {
    const float* node_attrs = (const float*)d_in[0];
    const float* positions  = (const float*)d_in[1];
    const int*   edge_index = (const int*)d_in[2];
    const float* proj_W   = (const float*)d_in[3];
    const float* emb_in_W = (const float*)d_in[4];
    const float* emb_in_b = (const float*)d_in[5];
    const float* edge_W1  = (const float*)d_in[6];
    const float* edge_b1  = (const float*)d_in[7];
    const float* edge_W2  = (const float*)d_in[8];
    const float* edge_b2  = (const float*)d_in[9];
    const float* node_W1  = (const float*)d_in[10];
    const float* node_b1  = (const float*)d_in[11];
    const float* node_W2  = (const float*)d_in[12];
    const float* node_b2  = (const float*)d_in[13];
    const float* coord_W1 = (const float*)d_in[14];
    const float* coord_b1 = (const float*)d_in[15];
    const float* coord_W2 = (const float*)d_in[16];
    const float* lin_W    = (const float*)d_in[19];

    const int N = in_sizes[0] / 3;
    const int E = in_sizes[2] / 2;
    const int* row = edge_index;
    const int* col = edge_index + E;

    float* x0 = (float*)d_ws;
    float* h0 = x0 + (size_t)DOUT * N;
    float* x1 = h0 + (size_t)H * N;
    float* h1 = x1 + (size_t)DOUT * N;
    float* xsum = h1 + (size_t)H * N;          // 16N
    float* magg = xsum + (size_t)DOUT * N;     // 32N (adjacent -> one memset)
    ushort_t* hb   = (ushort_t*)(magg + (size_t)H * N);
    ushort_t* W1B  = hb + (size_t)H * N;       // 6144
    ushort_t* W2B  = W1B + 6144;               // 2048
    ushort_t* CW1B = W2B + 2048;               // 2048
    ushort_t* NW1B = CW1B + 2048;              // 4096
    ushort_t* NW2B = NW1B + 4096;              // 2048
    int* deg    = (int*)(NW2B + 2048);
    int* startv = deg + N;
    int* cursor = startv + N;
    int2* ee    = (int2*)(cursor + N);

    int nB256 = (N + 255) / 256;
    int eB256 = (E + 255) / 256;
    int tBlocks = (E + 63) / 64;
    int nTiles = (N + 63) / 64;
    int ipBlocks = (N + 6144 + 255) / 256;

    hipMemsetAsync(deg, 0, (size_t)N * sizeof(int), stream);
    hipMemsetAsync(xsum, 0, (size_t)(DOUT + H) * N * sizeof(float), stream);

    hist_kernel<<<eB256, 256, 0, stream>>>(row, deg, E);
    init_pack<<<ipBlocks, 256, 0, stream>>>(
        node_attrs, positions, proj_W, emb_in_W, emb_in_b,
        edge_W1, edge_b1, edge_W2, coord_W1, node_W1, node_W2,
        x0, h0, hb, W1B, W2B, CW1B, NW1B, NW2B, N);
    scan_kernel<<<1, 1024, 0, stream>>>(deg, startv, cursor, N);
    scatter_kernel<<<eB256, 256, 0, stream>>>(row, col, cursor, ee, E);

    const float* xi = x0; const float* hi = h0;
    float* xo = x1; float* ho = h1;
    for (int l = 0; l < 2; ++l) {
        edge_mfma<<<tBlocks, 256, 0, stream>>>(
            ee, positions, xi, hb,
            W1B + (size_t)l * 3072, W2B + (size_t)l * 1024, CW1B + (size_t)l * 1024,
            edge_b2 + l * H, coord_b1 + l * H, coord_W2 + l * H,
            xsum, magg, E);
        node_mfma<<<nTiles, 256, 0, stream>>>(
            deg, xi, hi, hb, xsum, magg,
            NW1B + (size_t)l * 2048, NW2B + (size_t)l * 1024,
            node_b1 + l * H, node_b2 + l * H,
            xo, ho, hb, N);
        const float* tx = xi; xi = xo; xo = (float*)tx;
        const float* th = hi; hi = ho; ho = (float*)th;
    }

    out_kernel<<<nB256, 256, 0, stream>>>(xi, lin_W, (float*)d_out, N);
}

// Round 13
// 594.853 us; speedup vs baseline: 2.8979x; 1.1991x over previous
//
#include <hip/hip_runtime.h>
#include <hip/hip_bf16.h>

#define H 32
#define DOUT 16
#define APITCH 104   // ushorts per A row (208 B)
#define NPITCH 72    // ushorts per node A row (144 B)

typedef unsigned short ushort_t;
typedef __attribute__((ext_vector_type(8))) short bf16x8;
typedef __attribute__((ext_vector_type(4))) float f32x4;

__device__ __forceinline__ float silu(float v) {
    return v * __builtin_amdgcn_rcpf(1.0f + __expf(-v));
}
__device__ __forceinline__ ushort_t f2bf(float f) {
    unsigned int u = __float_as_uint(f);
    unsigned int r = (u + 0x7FFFu + ((u >> 16) & 1u)) >> 16;  // RNE
    return (ushort_t)r;
}
__device__ __forceinline__ unsigned pk2bf(float a, float b) {  // packed RNE pair
    __hip_bfloat162 h = __float22bfloat162_rn(make_float2(a, b));
    return *reinterpret_cast<unsigned*>(&h);
}
__device__ __forceinline__ float bf2f(ushort_t h) {
    return __uint_as_float(((unsigned int)h) << 16);
}

// ---- CSR build -------------------------------------------------------------
__global__ __launch_bounds__(256) void hist_kernel(const int* __restrict__ row,
                                                   int* __restrict__ deg, int E) {
    int e = blockIdx.x * blockDim.x + threadIdx.x;
    if (e < E) atomicAdd(&deg[row[e]], 1);
}

// parallel exclusive scan, 3 phases (old single-block scan ran on one CU)
__global__ __launch_bounds__(256) void scan_part(const int* __restrict__ deg,
                                                 int* __restrict__ bsum, int N) {
    int i = blockIdx.x * 256 + threadIdx.x;
    int v = (i < N) ? deg[i] : 0;
    #pragma unroll
    for (int m = 1; m < 64; m <<= 1) v += __shfl_xor(v, m, 64);
    __shared__ int ws[4];
    if ((threadIdx.x & 63) == 0) ws[threadIdx.x >> 6] = v;
    __syncthreads();
    if (threadIdx.x == 0) bsum[blockIdx.x] = ws[0] + ws[1] + ws[2] + ws[3];
}

__global__ __launch_bounds__(256) void scan_mid(int* __restrict__ bsum, int nb) {
    __shared__ int sh[256];
    int t = threadIdx.x;
    int v = (t < nb) ? bsum[t] : 0;
    sh[t] = v;
    __syncthreads();
    for (int off = 1; off < 256; off <<= 1) {
        int u = (t >= off) ? sh[t - off] : 0;
        __syncthreads();
        sh[t] += u;
        __syncthreads();
    }
    if (t < nb) bsum[t] = sh[t] - v;  // exclusive
}

__global__ __launch_bounds__(256) void scan_write(const int* __restrict__ deg,
                                                  const int* __restrict__ boffs,
                                                  int* __restrict__ cursor, int N) {
    int i = blockIdx.x * 256 + threadIdx.x;
    int lane = threadIdx.x & 63, w = threadIdx.x >> 6;
    int v = (i < N) ? deg[i] : 0;
    int x = v;
    #pragma unroll
    for (int off = 1; off < 64; off <<= 1) {
        int y = __shfl_up(x, off, 64);
        if (lane >= off) x += y;
    }
    __shared__ int wsum[4];
    if (lane == 63) wsum[w] = x;
    __syncthreads();
    int woff = 0;
    for (int k = 0; k < w; ++k) woff += wsum[k];
    if (i < N) cursor[i] = boffs[blockIdx.x] + woff + x - v;
}

// one scattered int2 store per edge: ee[p] = {col, row}
__global__ __launch_bounds__(256) void scatter_kernel(const int* __restrict__ row,
                                                      const int* __restrict__ col,
                                                      int* __restrict__ cursor,
                                                      int2* __restrict__ ee, int E) {
    int e = blockIdx.x * blockDim.x + threadIdx.x;
    if (e < E) {
        int r = row[e];
        int p = atomicAdd(&cursor[r], 1);
        ee[p] = make_int2(col[e], r);
    }
}

// ---- fused init (x, h fp32 + bf16 mirror) + weight pack --------------------
__global__ __launch_bounds__(256) void init_pack(
    const float* __restrict__ node_attrs, const float* __restrict__ positions,
    const float* __restrict__ projW, const float* __restrict__ embW,
    const float* __restrict__ embB,
    const float* __restrict__ eW1, const float* __restrict__ eb1,
    const float* __restrict__ eW2, const float* __restrict__ cW1,
    const float* __restrict__ nW1, const float* __restrict__ nW2,
    float* __restrict__ x, float* __restrict__ h, ushort_t* __restrict__ hb,
    ushort_t* __restrict__ W1B, ushort_t* __restrict__ W2B,
    ushort_t* __restrict__ CW1B, ushort_t* __restrict__ NW1B,
    ushort_t* __restrict__ NW2B, int N)
{
    int g = blockIdx.x * blockDim.x + threadIdx.x;
    if (g < N) {
        int n = g;
        float p0 = positions[3*n+0], p1 = positions[3*n+1], p2 = positions[3*n+2];
        #pragma unroll
        for (int i = 0; i < DOUT; ++i)
            x[(size_t)n*DOUT+i] = projW[i*3+0]*p0 + projW[i*3+1]*p1 + projW[i*3+2]*p2;
        float a0 = node_attrs[3*n+0], a1 = node_attrs[3*n+1], a2 = node_attrs[3*n+2];
        #pragma unroll
        for (int j = 0; j < H; ++j) {
            float v = embB[j] + embW[j*3+0]*a0 + embW[j*3+1]*a1 + embW[j*3+2]*a2;
            h[(size_t)n*H+j] = v;
            hb[(size_t)n*H+j] = f2bf(v);
        }
        return;
    }
    int t = g - N;
    if (t < 6144) {  // edge W1: K=96 padded, bias baked at k=68
        int j = t & 7; int r1 = t >> 3;
        int lane = r1 & 63; int r2 = r1 >> 6;
        int nt = r2 & 1; int r3 = r2 >> 1;
        int kc = r3 % 3; int l = r3 / 3;
        int n = 16 * nt + (lane & 15);
        int k = 32 * kc + 8 * (lane >> 4) + j;
        float v = 0.0f;
        if (k < 68) v = eW1[(l * 32 + n) * 68 + k];
        else if (k == 68) v = eb1[l * 32 + n];
        W1B[t] = f2bf(v);
    }
    if (t < 4096) {  // node W1: K=64
        int j = t & 7; int lane = (t >> 3) & 63;
        int nt = (t >> 9) & 1; int kc = (t >> 10) & 1; int l = (t >> 11) & 1;
        int n = 16 * nt + (lane & 15);
        int k = 32 * kc + 8 * (lane >> 4) + j;
        NW1B[t] = f2bf(nW1[(l * 32 + n) * 64 + k]);
    }
    if (t < 2048) {  // edge W2 / coord W1 / node W2: K=32
        int j = t & 7; int lane = (t >> 3) & 63;
        int nt = (t >> 9) & 1; int l = t >> 10;
        int n = 16 * nt + (lane & 15);
        int k = 8 * (lane >> 4) + j;
        W2B[t]  = f2bf(eW2[(l * 32 + n) * 32 + k]);
        CW1B[t] = f2bf(cW1[(l * 32 + n) * 32 + k]);
        NW2B[t] = f2bf(nW2[(l * 32 + n) * 32 + k]);
    }
}

// ---- MFMA edge kernel: 64 edges/block --------------------------------------
__global__ __launch_bounds__(256) void edge_mfma(
    const int2* __restrict__ ee,
    const float* __restrict__ positions,
    const float* __restrict__ x_in, const ushort_t* __restrict__ hbf,
    const ushort_t* __restrict__ W1B, const ushort_t* __restrict__ W2B,
    const ushort_t* __restrict__ CW1B,
    const float* __restrict__ eb2, const float* __restrict__ cb1,
    const float* __restrict__ cw2,
    float* __restrict__ xsum, float* __restrict__ magg, int E)
{
    __shared__ __align__(16) ushort_t Ain[64 * APITCH];  // wave slab reused for m1 then m2 (bf16)
    __shared__ __align__(16) float    CDs[64 * 20];
    __shared__ float RP[256];
    __shared__ float CMs[64];
    __shared__ int ERO[64];
    __shared__ int RSTART[65];
    __shared__ int RNODE[64];
    __shared__ int NRUN;

    const int tid = threadIdx.x;
    const int t0 = blockIdx.x * 64;
    const int ntile = min(64, E - t0);
    const int lane = tid & 63;
    const int w = tid >> 6;
    const int nidx = lane & 15;
    const int q = lane >> 4;

    bf16x8 w1f[3][2], w2f[2], cwf[2];
    #pragma unroll
    for (int kc = 0; kc < 3; ++kc)
        #pragma unroll
        for (int nt = 0; nt < 2; ++nt)
            w1f[kc][nt] = *(const bf16x8*)(W1B + ((size_t)((kc*2+nt)*64 + lane)) * 8);
    #pragma unroll
    for (int nt = 0; nt < 2; ++nt) {
        w2f[nt] = *(const bf16x8*)(W2B + (size_t)(nt*64 + lane) * 8);
        cwf[nt] = *(const bf16x8*)(CW1B + (size_t)(nt*64 + lane) * 8);
    }
    float eb2v0 = eb2[nidx], eb2v1 = eb2[16 + nidx];
    float cb1v0 = cb1[nidx], cb1v1 = cb1[16 + nidx];
    float cw2v0 = cw2[nidx], cw2v1 = cw2[16 + nidx];

    // ---- Phase A0: zero K-tail, copy h bf16, cd partials -------------------
    {
        int rr = tid >> 2, seg = tid & 3;
        *(uint4*)((char*)Ain + rr * 208 + 128 + seg * 16) = make_uint4(0,0,0,0);
    }
    {
        int e = tid >> 2, part = tid & 3;
        int s = t0 + e;
        uint4 v0 = make_uint4(0,0,0,0), v1 = v0;
        if (s < E) {
            int2 p = ee[s];
            int node = (part < 2) ? p.y : p.x;
            const uint4* hp = (const uint4*)(hbf + (size_t)node * H + (part & 1) * 16);
            v0 = hp[0]; v1 = hp[1];
        }
        uint4* dst = (uint4*)((char*)Ain + e * 208 + part * 32);
        dst[0] = v0; dst[1] = v1;
    }
    {
        int e = tid >> 2, qq = tid & 3;
        int s = t0 + e;
        float part = 0.0f;
        if (s < E) {
            int2 p = ee[s];
            float4 a = *(const float4*)(x_in + (size_t)p.y * DOUT + 4 * qq);
            float4 b = *(const float4*)(x_in + (size_t)p.x * DOUT + 4 * qq);
            float4 d;
            d.x = a.x - b.x; d.y = a.y - b.y; d.z = a.z - b.z; d.w = a.w - b.w;
            *(float4*)(CDs + e * 20 + 4 * qq) = d;
            part = d.x*d.x + d.y*d.y + d.z*d.z + d.w*d.w;
        }
        RP[tid] = part;
    }
    __syncthreads();

    // ---- Phase A1 (wave 0): radial, edge_attr, bias-one, ERO ---------------
    if (tid < 64) {
        int s = t0 + tid;
        if (s < E) {
            int2 p = ee[s];
            ERO[tid] = p.y;
            float radial = RP[4*tid] + RP[4*tid+1] + RP[4*tid+2] + RP[4*tid+3];
            ushort_t* rowp = Ain + tid * APITCH;
            rowp[64] = f2bf(radial);
            rowp[65] = f2bf(positions[3*p.y+0] - positions[3*p.x+0]);
            rowp[66] = f2bf(positions[3*p.y+1] - positions[3*p.x+1]);
            rowp[67] = f2bf(positions[3*p.y+2] - positions[3*p.x+2]);
            rowp[68] = 0x3F80;  // bf16(1.0) pairs with baked eb1
        } else {
            ERO[tid] = -1;
        }
    }
    __syncthreads();

    // ---- Phase B: MLP1 (68->32), K=96, 6 MFMAs -----------------------------
    const int mrow = 16 * w + nidx;
    bf16x8 af0 = *(const bf16x8*)(Ain + mrow * APITCH + 0  + 8 * q);
    bf16x8 af1 = *(const bf16x8*)(Ain + mrow * APITCH + 32 + 8 * q);
    bf16x8 af2 = *(const bf16x8*)(Ain + mrow * APITCH + 64 + 8 * q);
    f32x4 z4 = {0.0f, 0.0f, 0.0f, 0.0f};
    f32x4 acc0 = z4, acc1 = z4;
    acc0 = __builtin_amdgcn_mfma_f32_16x16x32_bf16(af0, w1f[0][0], acc0, 0, 0, 0);
    acc0 = __builtin_amdgcn_mfma_f32_16x16x32_bf16(af1, w1f[1][0], acc0, 0, 0, 0);
    acc0 = __builtin_amdgcn_mfma_f32_16x16x32_bf16(af2, w1f[2][0], acc0, 0, 0, 0);
    acc1 = __builtin_amdgcn_mfma_f32_16x16x32_bf16(af0, w1f[0][1], acc1, 0, 0, 0);
    acc1 = __builtin_amdgcn_mfma_f32_16x16x32_bf16(af1, w1f[1][1], acc1, 0, 0, 0);
    acc1 = __builtin_amdgcn_mfma_f32_16x16x32_bf16(af2, w1f[2][1], acc1, 0, 0, 0);

    ushort_t* m1w = Ain + w * 16 * APITCH;   // own-slab reuse (m1, pitch 40)
    #pragma unroll
    for (int r = 0; r < 4; ++r) {
        unsigned u = pk2bf(silu(acc0[r]), silu(acc1[r]));
        m1w[(4*q + r) * 40 + nidx]      = (ushort_t)(u & 0xFFFFu);
        m1w[(4*q + r) * 40 + 16 + nidx] = (ushort_t)(u >> 16);
    }

    // ---- Phase C: MLP2 (32->32); m2 bf16 overwrites m1 (same pitch) --------
    bf16x8 a2 = *(const bf16x8*)(m1w + nidx * 40 + 8 * q);
    f32x4 b0 = __builtin_amdgcn_mfma_f32_16x16x32_bf16(a2, w2f[0], z4, 0, 0, 0);
    f32x4 b1 = __builtin_amdgcn_mfma_f32_16x16x32_bf16(a2, w2f[1], z4, 0, 0, 0);
    #pragma unroll
    for (int r = 0; r < 4; ++r) {
        unsigned u = pk2bf(silu(b0[r] + eb2v0), silu(b1[r] + eb2v1));
        m1w[(4*q + r) * 40 + nidx]      = (ushort_t)(u & 0xFFFFu);
        m1w[(4*q + r) * 40 + 16 + nidx] = (ushort_t)(u >> 16);
    }

    // ---- Phase D: coord MLP (A-frag read directly as bf16) -----------------
    bf16x8 a3 = *(const bf16x8*)(m1w + nidx * 40 + 8 * q);
    f32x4 c0 = __builtin_amdgcn_mfma_f32_16x16x32_bf16(a3, cwf[0], z4, 0, 0, 0);
    f32x4 c1 = __builtin_amdgcn_mfma_f32_16x16x32_bf16(a3, cwf[1], z4, 0, 0, 0);
    float p[4];
    #pragma unroll
    for (int r = 0; r < 4; ++r)
        p[r] = silu(c0[r] + cb1v0) * cw2v0 + silu(c1[r] + cb1v1) * cw2v1;
    #pragma unroll
    for (int m = 1; m < 16; m <<= 1) {
        #pragma unroll
        for (int r = 0; r < 4; ++r) p[r] += __shfl_xor(p[r], m, 64);
    }
    if (nidx == 0) {
        #pragma unroll
        for (int r = 0; r < 4; ++r) CMs[16*w + 4*q + r] = p[r];
    }
    __syncthreads();

    // ---- Phase E: ballot run detection + segmented sums + few atomics ------
    if (tid < 64) {
        bool f = (tid < ntile) && (tid == 0 || ERO[tid] != ERO[tid - 1]);
        unsigned long long mask = __ballot(f);
        if (f) {
            int rank = (int)__popcll(mask & ((1ull << tid) - 1ull));
            RSTART[rank] = tid;
            RNODE[rank] = ERO[tid];
        }
        if (tid == 0) {
            int nr = (int)__popcll(mask);
            NRUN = nr;
            RSTART[nr] = ntile;
        }
    }
    __syncthreads();
    int nrun = NRUN;
    for (int idx = tid; idx < nrun * 48; idx += 256) {
        int k = idx / 48, d = idx - k * 48;
        int s = RSTART[k], en = RSTART[k + 1];
        int node = RNODE[k];
        float sum = 0.0f;
        if (d < 32) {
            for (int e = s; e < en; ++e)
                sum += bf2f(Ain[(e >> 4) * 16 * APITCH + (e & 15) * 40 + d]);
            unsafeAtomicAdd(&magg[(size_t)node * H + d], sum);
        } else {
            int dd = d - 32;
            for (int e = s; e < en; ++e)
                sum += CDs[e * 20 + dd] * CMs[e];
            unsafeAtomicAdd(&xsum[(size_t)node * DOUT + dd], sum);
        }
    }
}

// ---- MFMA node kernel: 64 nodes/block; optional fused output ---------------
__global__ __launch_bounds__(256) void node_mfma(
    const int* __restrict__ deg,
    const float* __restrict__ x_in, const float* __restrict__ h_in,
    const ushort_t* __restrict__ hbf_in,
    float* __restrict__ xsum, float* __restrict__ magg,
    const ushort_t* __restrict__ W1B, const ushort_t* __restrict__ W2B,
    const float* __restrict__ b1g, const float* __restrict__ b2g,
    float* __restrict__ x_out, float* __restrict__ h_out,
    ushort_t* __restrict__ hbf_out,
    const float* __restrict__ lin, float* __restrict__ outp, int N)
{
    __shared__ __align__(16) ushort_t Nin[64 * NPITCH];

    const int tid = threadIdx.x;
    const int n0 = blockIdx.x * 64;
    const int lane = tid & 63;
    const int w = tid >> 6;
    const int nidx = lane & 15;
    const int q = lane >> 4;

    bf16x8 w1f[2][2], w2f[2];
    #pragma unroll
    for (int kc = 0; kc < 2; ++kc)
        #pragma unroll
        for (int nt = 0; nt < 2; ++nt)
            w1f[kc][nt] = *(const bf16x8*)(W1B + (size_t)((kc*2+nt)*64 + lane) * 8);
    #pragma unroll
    for (int nt = 0; nt < 2; ++nt)
        w2f[nt] = *(const bf16x8*)(W2B + (size_t)(nt*64 + lane) * 8);
    float b1v0 = b1g[nidx], b1v1 = b1g[16+nidx];
    float b2v0 = b2g[nidx], b2v1 = b2g[16+nidx];

    // stage nin = [h bf16 | magg->bf16]; zero magg after read (skip last layer)
    {
        int e = tid >> 2, part = tid & 3;
        int n = n0 + e;
        uint4 v0 = make_uint4(0,0,0,0), v1 = v0;
        if (n < N) {
            if (part < 2) {
                const uint4* hp = (const uint4*)(hbf_in + (size_t)n * H + part * 16);
                v0 = hp[0]; v1 = hp[1];
            } else {
                float4* mp = (float4*)(magg + (size_t)n * H + (part & 1) * 16);
                float4 f[4] = {mp[0], mp[1], mp[2], mp[3]};
                unsigned u[8];
                #pragma unroll
                for (int qq = 0; qq < 4; ++qq) {
                    u[2*qq]   = pk2bf(f[qq].x, f[qq].y);
                    u[2*qq+1] = pk2bf(f[qq].z, f[qq].w);
                }
                v0 = make_uint4(u[0], u[1], u[2], u[3]);
                v1 = make_uint4(u[4], u[5], u[6], u[7]);
                if (!lin) {
                    float4 z = {0.0f, 0.0f, 0.0f, 0.0f};
                    mp[0] = z; mp[1] = z; mp[2] = z; mp[3] = z;
                }
            }
        }
        uint4* dst = (uint4*)((char*)Nin + e * 144 + part * 32);
        dst[0] = v0; dst[1] = v1;
    }

    // x update (row per thread); zero xsum; fused output on last layer
    if (tid < 64) {
        int n = n0 + tid;
        if (n < N) {
            float inv = __builtin_amdgcn_rcpf(fmaxf((float)deg[n], 1.0f));
            const float4* xi4 = (const float4*)(x_in + (size_t)n * DOUT);
            float4* xs4 = (float4*)(xsum + (size_t)n * DOUT);
            float4* xo4 = (float4*)(x_out + (size_t)n * DOUT);
            float xr[DOUT];
            #pragma unroll
            for (int qq = 0; qq < DOUT/4; ++qq) {
                float4 a = xi4[qq], b = xs4[qq];
                float4 v;
                v.x = a.x + b.x*inv; v.y = a.y + b.y*inv;
                v.z = a.z + b.z*inv; v.w = a.w + b.w*inv;
                xo4[qq] = v;
                xr[4*qq+0]=v.x; xr[4*qq+1]=v.y; xr[4*qq+2]=v.z; xr[4*qq+3]=v.w;
                if (!lin) {
                    float4 z = {0.0f, 0.0f, 0.0f, 0.0f};
                    xs4[qq] = z;
                }
            }
            if (lin) {
                #pragma unroll
                for (int i = 0; i < 3; ++i) {
                    float a = 0.0f;
                    #pragma unroll
                    for (int k = 0; k < DOUT; ++k) a += xr[k] * lin[i*DOUT+k];
                    outp[(size_t)n*3+i] = a;
                }
            }
        }
    }
    __syncthreads();

    const int mrow = 16 * w + nidx;
    bf16x8 a0 = *(const bf16x8*)(Nin + mrow * NPITCH + 8 * q);
    bf16x8 a1 = *(const bf16x8*)(Nin + mrow * NPITCH + 32 + 8 * q);
    f32x4 z4 = {0.0f, 0.0f, 0.0f, 0.0f};
    f32x4 acc0 = z4, acc1 = z4;
    acc0 = __builtin_amdgcn_mfma_f32_16x16x32_bf16(a0, w1f[0][0], acc0, 0, 0, 0);
    acc0 = __builtin_amdgcn_mfma_f32_16x16x32_bf16(a1, w1f[1][0], acc0, 0, 0, 0);
    acc1 = __builtin_amdgcn_mfma_f32_16x16x32_bf16(a0, w1f[0][1], acc1, 0, 0, 0);
    acc1 = __builtin_amdgcn_mfma_f32_16x16x32_bf16(a1, w1f[1][1], acc1, 0, 0, 0);

    ushort_t* u1w = Nin + w * 16 * NPITCH;   // own slab reuse
    #pragma unroll
    for (int r = 0; r < 4; ++r) {
        unsigned u = pk2bf(silu(acc0[r] + b1v0), silu(acc1[r] + b1v1));
        u1w[(4*q + r) * 40 + nidx]      = (ushort_t)(u & 0xFFFFu);
        u1w[(4*q + r) * 40 + 16 + nidx] = (ushort_t)(u >> 16);
    }
    bf16x8 au = *(const bf16x8*)(u1w + nidx * 40 + 8 * q);
    f32x4 d0 = __builtin_amdgcn_mfma_f32_16x16x32_bf16(au, w2f[0], z4, 0, 0, 0);
    f32x4 d1 = __builtin_amdgcn_mfma_f32_16x16x32_bf16(au, w2f[1], z4, 0, 0, 0);
    #pragma unroll
    for (int r = 0; r < 4; ++r) {
        int n = n0 + 16*w + 4*q + r;
        if (n < N) {
            size_t o0 = (size_t)n * H + nidx, o1 = o0 + 16;
            float h0 = h_in[o0] + d0[r] + b2v0;
            float h1 = h_in[o1] + d1[r] + b2v1;
            h_out[o0] = h0; h_out[o1] = h1;
            hbf_out[o0] = f2bf(h0); hbf_out[o1] = f2bf(h1);
        }
    }
}

extern "C" void kernel_launch(void* const* d_in, const int* in_sizes, int n_in,
                              void* d_out, int out_size, void* d_ws, size_t ws_size,
                              hipStream_t stream) {
    const float* node_attrs = (const float*)d_in[0];
    const float* positions  = (const float*)d_in[1];
    const int*   edge_index = (const int*)d_in[2];
    const float* proj_W   = (const float*)d_in[3];
    const float* emb_in_W = (const float*)d_in[4];
    const float* emb_in_b = (const float*)d_in[5];
    const float* edge_W1  = (const float*)d_in[6];
    const float* edge_b1  = (const float*)d_in[7];
    const float* edge_W2  = (const float*)d_in[8];
    const float* edge_b2  = (const float*)d_in[9];
    const float* node_W1  = (const float*)d_in[10];
    const float* node_b1  = (const float*)d_in[11];
    const float* node_W2  = (const float*)d_in[12];
    const float* node_b2  = (const float*)d_in[13];
    const float* coord_W1 = (const float*)d_in[14];
    const float* coord_b1 = (const float*)d_in[15];
    const float* coord_W2 = (const float*)d_in[16];
    const float* lin_W    = (const float*)d_in[19];

    const int N = in_sizes[0] / 3;
    const int E = in_sizes[2] / 2;
    const int* row = edge_index;
    const int* col = edge_index + E;

    float* x0 = (float*)d_ws;
    float* h0 = x0 + (size_t)DOUT * N;
    float* x1 = h0 + (size_t)H * N;
    float* h1 = x1 + (size_t)DOUT * N;
    float* xsum = h1 + (size_t)H * N;          // 16N
    float* magg = xsum + (size_t)DOUT * N;     // 32N (adjacent -> one memset)
    ushort_t* hb   = (ushort_t*)(magg + (size_t)H * N);
    ushort_t* W1B  = hb + (size_t)H * N;       // 6144
    ushort_t* W2B  = W1B + 6144;               // 2048
    ushort_t* CW1B = W2B + 2048;               // 2048
    ushort_t* NW1B = CW1B + 2048;              // 4096
    ushort_t* NW2B = NW1B + 4096;              // 2048
    int* deg    = (int*)(NW2B + 2048);
    int* bsum   = deg + N;                     // 256 (scan partials)
    int* cursor = bsum + 256;
    int2* ee    = (int2*)(cursor + N);

    int nB256 = (N + 255) / 256;
    int eB256 = (E + 255) / 256;
    int tBlocks = (E + 63) / 64;
    int nTiles = (N + 63) / 64;
    int ipBlocks = (N + 6144 + 255) / 256;

    hipMemsetAsync(deg, 0, (size_t)N * sizeof(int), stream);
    hipMemsetAsync(xsum, 0, (size_t)(DOUT + H) * N * sizeof(float), stream);

    hist_kernel<<<eB256, 256, 0, stream>>>(row, deg, E);
    init_pack<<<ipBlocks, 256, 0, stream>>>(
        node_attrs, positions, proj_W, emb_in_W, emb_in_b,
        edge_W1, edge_b1, edge_W2, coord_W1, node_W1, node_W2,
        x0, h0, hb, W1B, W2B, CW1B, NW1B, NW2B, N);
    scan_part<<<nB256, 256, 0, stream>>>(deg, bsum, N);
    scan_mid<<<1, 256, 0, stream>>>(bsum, nB256);
    scan_write<<<nB256, 256, 0, stream>>>(deg, bsum, cursor, N);
    scatter_kernel<<<eB256, 256, 0, stream>>>(row, col, cursor, ee, E);

    const float* xi = x0; const float* hi = h0;
    float* xo = x1; float* ho = h1;
    for (int l = 0; l < 2; ++l) {
        edge_mfma<<<tBlocks, 256, 0, stream>>>(
            ee, positions, xi, hb,
            W1B + (size_t)l * 3072, W2B + (size_t)l * 1024, CW1B + (size_t)l * 1024,
            edge_b2 + l * H, coord_b1 + l * H, coord_W2 + l * H,
            xsum, magg, E);
        node_mfma<<<nTiles, 256, 0, stream>>>(
            deg, xi, hi, hb, xsum, magg,
            NW1B + (size_t)l * 2048, NW2B + (size_t)l * 1024,
            node_b1 + l * H, node_b2 + l * H,
            xo, ho, hb,
            (l == 1) ? lin_W : nullptr, (l == 1) ? (float*)d_out : nullptr, N);
        const float* tx = xi; xi = xo; xo = (float*)tx;
        const float* th = hi; hi = ho; ho = (float*)th;
    }
}